// Round 9
// baseline (6469.517 us; speedup 1.0000x reference)
//
#include <hip/hip_runtime.h>
#include <hip/hip_bf16.h>
#include <stdint.h>

typedef __attribute__((ext_vector_type(8))) short short8;
typedef __attribute__((ext_vector_type(4))) float f32x4;
typedef __attribute__((ext_vector_type(4))) int int4v;

__device__ __forceinline__ float bf2f(unsigned short u) {
  union { unsigned int i; float f; } v; v.i = ((unsigned int)u) << 16; return v.f;
}
__device__ __forceinline__ unsigned short f2bf(float f) {
  union { float f; unsigned int i; } v; v.f = f;
  unsigned int i = v.i;
  i += 0x7FFFu + ((i >> 16) & 1u);
  return (unsigned short)(i >> 16);
}
__device__ __forceinline__ float tanh_fast(float x) {
  float e = __expf(2.0f * x);
  return 1.0f - 2.0f / (e + 1.0f);
}

// ---------------- weight prep ----------------
// ODE: wimg[arr(hi/lo)][icb][oc][tap][icm] per layer (73728 elems/layer), bf16
// decoder (ic-contiguous): s1wt[kk][oc32][ic64], s2wt[kk][oc16][ic32], s3wt[kk][ic16]
__global__ void prep_weights(const float* __restrict__ w1, const float* __restrict__ w2,
                             const float* __restrict__ w3, const float* __restrict__ w4,
                             const float* __restrict__ s1w, const float* __restrict__ s2w,
                             const float* __restrict__ s3w,
                             unsigned short* __restrict__ wimg,
                             float* __restrict__ s1wt, float* __restrict__ s2wt,
                             float* __restrict__ s3wt) {
  int t = blockIdx.x * 256 + threadIdx.x;
  if (t < 147456) {
    int l = t / 36864;
    int oc = (t / 576) & 63;
    int ic = (t / 9) & 63;
    int tap = t % 9;
    const float* w = (l == 0) ? w1 : (l == 1) ? w2 : (l == 2) ? w3 : w4;
    float v = w[(oc * 64 + ic) * 9 + tap];
    unsigned short hi = f2bf(v);
    unsigned short lo = f2bf(v - bf2f(hi));
    int icb = ic >> 5, icm = ic & 31;
    int idx = (icb * 64 + oc) * 288 + tap * 32 + icm;
    wimg[l * 73728 + idx]         = hi;
    wimg[l * 73728 + 36864 + idx] = lo;
  } else if (t < 180224) {
    int u = t - 147456;                       // [kk][oc][ic64]
    int ic = u & 63, oc = (u >> 6) & 31, kk = u >> 11;
    int ky = kk >> 2, kx = kk & 3;
    s1wt[u] = s1w[((oc * 64 + ic) * 4 + ky) * 4 + kx];
  } else if (t < 188416) {
    int u = t - 180224;                       // [kk][oc][ic32]
    int ic = u & 31, oc = (u >> 5) & 15, kk = u >> 9;
    int ky = kk >> 2, kx = kk & 3;
    s2wt[u] = s2w[((oc * 32 + ic) * 4 + ky) * 4 + kx];
  } else if (t < 188560) {
    int u = t - 188416;                       // [kk][ic16]
    int ic = u & 15, kk = u >> 4;
    int ky = kk / 3, kx = kk % 3;
    s3wt[u] = s3w[ic * 9 + ky * 3 + kx];
  }
}

// NCHW h_s0 -> NHWC bf16 pair (S0) + f32 outs[0]
__global__ void prep_state(const float* __restrict__ src,
                           unsigned short* __restrict__ s0h, unsigned short* __restrict__ s0l,
                           float* __restrict__ outs0) {
  int t = blockIdx.x * 256 + threadIdx.x;    // NHWC flat: ((b*32+h)*32+w)*64+c
  int c = t & 63, w = (t >> 6) & 31, h = (t >> 11) & 31, b = t >> 16;
  float v = src[((b * 64 + c) * 32 + h) * 32 + w];
  unsigned short hi = f2bf(v);
  s0h[t] = hi;
  s0l[t] = f2bf(v - bf2f(hi));
  outs0[t] = v;
}

// ---------------- ODE conv body: 1024 thr, 16 waves -----------------------------
// wave wv: kq = wv>>2 (K-split quarter), tl = wv&3 -> (mt = tl>>1, nt = tl&1)
// wave tile = M32 (row h0+mt) x N32 (oc nt*32..+31), 2x2 of 16x16x32 MFMA.
// A in LDS [arr2][row4][w34][144B] = 39168 B; B straight from global (L2) to regs.
// K-split partials reduced via LDS region (12 slots x 5120 B, stride 80 pad).
#define LDS_A_ARR 19584
#define REDBASE 39168
#define CONV_LDS 100608

__device__ __forceinline__ void conv_body(
    uint8_t* lds, int b, int h0,
    const unsigned short* __restrict__ inHi, const unsigned short* __restrict__ inLo,
    const unsigned short* __restrict__ wimgL, const float* __restrict__ bias,
    unsigned short* __restrict__ outHi, unsigned short* __restrict__ outLo,
    f32x4* Y, f32x4* R, float* __restrict__ outsPtr, int mode) {
  const int tid = threadIdx.x;

  // ---- stage A-tile (rows h0-1..h0+2, w1 0..33 padded, 8x16B ic-chunks, hi+lo)
  for (int idx = tid; idx < 2176; idx += 1024) {
    int arr = idx / 1088;
    int r2 = idx - arr * 1088;
    int c = r2 & 7;
    int w1 = (r2 >> 3) % 34;
    int row = (r2 >> 3) / 34;
    int hp = h0 - 1 + row;
    int w = w1 - 1;
    int4v v = {0, 0, 0, 0};
    if (hp >= 0 && hp < 32 && w >= 0 && w < 32) {
      const unsigned short* sp = arr ? inLo : inHi;
      v = *(const int4v*)(sp + (((b * 32 + hp) * 32 + w) * 64 + c * 8));
    }
    *(int4v*)(lds + ((arr * 4 + row) * 34 + w1) * 144 + c * 16) = v;
  }
  __syncthreads();

  const int lane = tid & 63;
  const int wv = tid >> 6;
  const int kq = wv >> 2;
  const int tl = wv & 3;
  const int mt = tl >> 1;
  const int nt = tl & 1;
  const int lmod = lane & 15;
  const int lg = lane >> 4;

  // B global element-offsets: ((arr*2+icb)*64 + nt*32 + nsub*16 + lmod)*288 + tap*32 + lg*8
  const int wo00 = (nt * 32 + lmod) * 288 + lg * 8;   // arr0 nsub0 (icb/tap added below)
  const int wo01 = wo00 + 16 * 288;                   // arr0 nsub1
  const int wo10 = wo00 + 36864;                      // arr1 nsub0
  const int wo11 = wo10 + 16 * 288;

  f32x4 acc00 = {0.f,0.f,0.f,0.f}, acc01 = {0.f,0.f,0.f,0.f};
  f32x4 acc10 = {0.f,0.f,0.f,0.f}, acc11 = {0.f,0.f,0.f,0.f};

  const int cnt = (kq < 2) ? 5 : 4;
  const int s0 = (kq < 2) ? kq * 5 : 10 + (kq - 2) * 4;

  short8 B0[4], B1[4];
  {
    int s = s0, icb = (s >= 9), tp = s - icb * 9, d = icb * 18432 + tp * 32;
    B0[0] = *(const short8*)(wimgL + wo00 + d);
    B0[1] = *(const short8*)(wimgL + wo01 + d);
    B0[2] = *(const short8*)(wimgL + wo10 + d);
    B0[3] = *(const short8*)(wimgL + wo11 + d);
  }
#pragma unroll
  for (int u = 0; u < 5; ++u) {
    if (u < cnt) {
      if (u + 1 < cnt) {
        int s = s0 + u + 1, icb = (s >= 9), tp = s - icb * 9, d = icb * 18432 + tp * 32;
        B1[0] = *(const short8*)(wimgL + wo00 + d);
        B1[1] = *(const short8*)(wimgL + wo01 + d);
        B1[2] = *(const short8*)(wimgL + wo10 + d);
        B1[3] = *(const short8*)(wimgL + wo11 + d);
      }
      {
        int s = s0 + u, icb = (s >= 9), tp = s - icb * 9;
        int dy = tp / 3, dx = tp % 3;
        int ab0 = (((mt + dy) * 34) + (lmod + dx)) * 144 + (icb * 4 + lg) * 16;
        int ab1 = ab0 + 16 * 144;
        short8 ah0 = *(const short8*)(lds + ab0);
        short8 al0 = *(const short8*)(lds + ab0 + LDS_A_ARR);
        short8 ah1 = *(const short8*)(lds + ab1);
        short8 al1 = *(const short8*)(lds + ab1 + LDS_A_ARR);
        acc00 = __builtin_amdgcn_mfma_f32_16x16x32_bf16(ah0, B0[0], acc00, 0, 0, 0);
        acc00 = __builtin_amdgcn_mfma_f32_16x16x32_bf16(al0, B0[0], acc00, 0, 0, 0);
        acc00 = __builtin_amdgcn_mfma_f32_16x16x32_bf16(ah0, B0[2], acc00, 0, 0, 0);
        acc01 = __builtin_amdgcn_mfma_f32_16x16x32_bf16(ah0, B0[1], acc01, 0, 0, 0);
        acc01 = __builtin_amdgcn_mfma_f32_16x16x32_bf16(al0, B0[1], acc01, 0, 0, 0);
        acc01 = __builtin_amdgcn_mfma_f32_16x16x32_bf16(ah0, B0[3], acc01, 0, 0, 0);
        acc10 = __builtin_amdgcn_mfma_f32_16x16x32_bf16(ah1, B0[0], acc10, 0, 0, 0);
        acc10 = __builtin_amdgcn_mfma_f32_16x16x32_bf16(al1, B0[0], acc10, 0, 0, 0);
        acc10 = __builtin_amdgcn_mfma_f32_16x16x32_bf16(ah1, B0[2], acc10, 0, 0, 0);
        acc11 = __builtin_amdgcn_mfma_f32_16x16x32_bf16(ah1, B0[1], acc11, 0, 0, 0);
        acc11 = __builtin_amdgcn_mfma_f32_16x16x32_bf16(al1, B0[1], acc11, 0, 0, 0);
        acc11 = __builtin_amdgcn_mfma_f32_16x16x32_bf16(ah1, B0[3], acc11, 0, 0, 0);
      }
#pragma unroll
      for (int q = 0; q < 4; ++q) B0[q] = B1[q];
    }
  }

  // ---- K-split reduction: kq>0 write partials; kq==0 accumulates
  if (kq > 0) {
    int base = REDBASE + ((kq - 1) * 4 + tl) * 5120 + lane * 80;
    *(f32x4*)(lds + base +  0) = acc00;
    *(f32x4*)(lds + base + 16) = acc01;
    *(f32x4*)(lds + base + 32) = acc10;
    *(f32x4*)(lds + base + 48) = acc11;
  }
  __syncthreads();

  if (kq == 0) {
#pragma unroll
    for (int p = 0; p < 3; ++p) {
      int base = REDBASE + (p * 4 + tl) * 5120 + lane * 80;
      acc00 += *(const f32x4*)(lds + base +  0);
      acc01 += *(const f32x4*)(lds + base + 16);
      acc10 += *(const f32x4*)(lds + base + 32);
      acc11 += *(const f32x4*)(lds + base + 48);
    }
    // ---- epilogue: D col = lane&15 (oc), row = lg*4+j (px); 4 quadrants
#pragma unroll
    for (int msub = 0; msub < 2; ++msub) {
#pragma unroll
      for (int nsub = 0; nsub < 2; ++nsub) {
        const int q = msub * 2 + nsub;
        f32x4 accv = (q == 0) ? acc00 : (q == 1) ? acc01 : (q == 2) ? acc10 : acc11;
        const int oc = nt * 32 + nsub * 16 + lmod;
        const float bz = bias[oc];
#pragma unroll
        for (int j = 0; j < 4; ++j) {
          const int px = mt * 32 + msub * 16 + lg * 4 + j;
          const int e = (b * 1024 + h0 * 32 + px) * 64 + oc;
          float kv = accv[j] + bz;
          if (mode == 0) {                    // conv + tanh -> pair
            float v = tanh_fast(kv);
            unsigned short hi = f2bf(v);
            outHi[e] = hi;
            outLo[e] = f2bf(v - bf2f(hi));
          } else if (mode == 1) {             // k1: z=y+0.25k ; R=y+k/12
            float z = fmaf(0.25f, kv, Y[q][j]);
            R[q][j] = fmaf(1.0f / 12.0f, kv, Y[q][j]);
            unsigned short hi = f2bf(z);
            outHi[e] = hi;
            outLo[e] = f2bf(z - bf2f(hi));
          } else if (mode == 2 || mode == 3) { // k2/k3
            float cz = (mode == 2) ? 0.25f : 0.5f;
            float z = fmaf(cz, kv, Y[q][j]);
            R[q][j] = fmaf(1.0f / 6.0f, kv, R[q][j]);
            unsigned short hi = f2bf(z);
            outHi[e] = hi;
            outLo[e] = f2bf(z - bf2f(hi));
          } else {                            // k4: ynew = R + k/12
            float z = fmaf(1.0f / 12.0f, kv, R[q][j]);
            Y[q][j] = z;
            unsigned short hi = f2bf(z);
            outHi[e] = hi;
            outLo[e] = f2bf(z - bf2f(hi));
            if (outsPtr) outsPtr[e] = z;
          }
        }
      }
    }
  }
  __syncthreads();
}

// ---------------- persistent ODE kernel: 64 blocks x 16 waves, neighbor-sync ---
__global__ __launch_bounds__(1024) void ode_persist(
    const unsigned short* __restrict__ wimg,
    const float* __restrict__ b1, const float* __restrict__ b2,
    const float* __restrict__ b3, const float* __restrict__ b4,
    unsigned short* __restrict__ S0h, unsigned short* __restrict__ S0l,
    unsigned short* __restrict__ S1h, unsigned short* __restrict__ S1l,
    unsigned short* __restrict__ T0h, unsigned short* __restrict__ T0l,
    unsigned short* __restrict__ T1h, unsigned short* __restrict__ T1l,
    float* __restrict__ outs, int* progress) {
  extern __shared__ uint8_t lds[];
  const int blk = blockIdx.x;
  const int b = blk >> 4;
  const int rp = blk & 15;
  const int h0 = rp << 1;
  const int nbA = (rp > 0) ? blk - 1 : -1;
  const int nbB = (rp < 15) ? blk + 1 : -1;

  const unsigned short* Wl[4] = {wimg, wimg + 73728, wimg + 147456, wimg + 221184};
  const float* Bl[4] = {b1, b2, b3, b4};

  // per-thread RK4 state on kq==0 waves: 16 outputs (4 quadrants x 4 px)
  const int lane = threadIdx.x & 63;
  const int wv = threadIdx.x >> 6;
  const int kq = wv >> 2, tl = wv & 3;
  const int mt = tl >> 1, nt = tl & 1;
  const int lmod = lane & 15, lg = lane >> 4;
  f32x4 Y[4], R[4];
  if (kq == 0) {
#pragma unroll
    for (int msub = 0; msub < 2; ++msub)
#pragma unroll
      for (int nsub = 0; nsub < 2; ++nsub) {
        const int q = msub * 2 + nsub;
#pragma unroll
        for (int j = 0; j < 4; ++j) {
          const int px = mt * 32 + msub * 16 + lg * 4 + j;
          const int e = (b * 1024 + h0 * 32 + px) * 64 + nt * 32 + nsub * 16 + lmod;
          Y[q][j] = outs[e];
          R[q][j] = 0.f;
        }
      }
  }

  int done = 0;
  for (int step = 1; step <= 18; ++step) {
    for (int sub = 0; sub < 4; ++sub) {
      for (int layer = 0; layer < 4; ++layer) {
        const unsigned short *iH, *iL;
        unsigned short *oH, *oL;
        int mode;
        float* op = nullptr;
        if (layer == 0) {
          iH = (sub == 0) ? S0h : S1h; iL = (sub == 0) ? S0l : S1l;
          oH = T0h; oL = T0l; mode = 0;
        } else if (layer == 1) {
          iH = T0h; iL = T0l; oH = T1h; oL = T1l; mode = 0;
        } else if (layer == 2) {
          iH = T1h; iL = T1l; oH = T0h; oL = T0l; mode = 0;
        } else {
          iH = T0h; iL = T0l;
          oH = (sub == 3) ? S0h : S1h; oL = (sub == 3) ? S0l : S1l;
          mode = 1 + sub;
          if (sub == 3 && (step & 1) == 0) op = outs + (size_t)(step >> 1) * 262144;
        }
        if (threadIdx.x == 0 && done > 0) {
          if (nbA >= 0)
            while (__hip_atomic_load(&progress[nbA], __ATOMIC_ACQUIRE,
                                     __HIP_MEMORY_SCOPE_AGENT) < done)
              __builtin_amdgcn_s_sleep(2);
          if (nbB >= 0)
            while (__hip_atomic_load(&progress[nbB], __ATOMIC_ACQUIRE,
                                     __HIP_MEMORY_SCOPE_AGENT) < done)
              __builtin_amdgcn_s_sleep(2);
          __threadfence();
        }
        __syncthreads();

        conv_body(lds, b, h0, iH, iL, Wl[layer], Bl[layer], oH, oL, Y, R, op, mode);

        ++done;
        if (threadIdx.x == 0) {
          __threadfence();
          __hip_atomic_store(&progress[blk], done, __ATOMIC_RELEASE,
                             __HIP_MEMORY_SCOPE_AGENT);
        }
      }
    }
  }
}

// ---------------- decoder (fp32, parity-direct taps, float4 loads) --------------
__global__ __launch_bounds__(256) void dec_s1(const float* __restrict__ in,
                                              const float* __restrict__ wt,
                                              const float* __restrict__ bs,
                                              float* __restrict__ out) {
  int t = blockIdx.x * 256 + threadIdx.x;
  int oc = t & 31, ox = (t >> 5) & 63, oy = (t >> 11) & 63, n = t >> 17;
  float a = bs[oc];
  int iyb = (oy - 2 + (oy & 1)) >> 1;
  int ixb = (ox - 2 + (ox & 1)) >> 1;
#pragma unroll
  for (int ay = 0; ay < 2; ++ay) {
    int iy = iyb + ay;
    if ((unsigned)iy >= 32u) continue;
    int ky = (oy & 1) + 2 * ay;
#pragma unroll
    for (int ax = 0; ax < 2; ++ax) {
      int ix = ixb + ax;
      if ((unsigned)ix >= 32u) continue;
      int kx = (ox & 1) + 2 * ax;
      const float4* xp = (const float4*)(in + ((n * 32 + iy) * 32 + ix) * 64);
      const float4* wp = (const float4*)(wt + ((ky * 4 + kx) * 32 + oc) * 64);
#pragma unroll
      for (int i4 = 0; i4 < 16; ++i4) {
        float4 xv = xp[i4], wv = wp[i4];
        a = fmaf(xv.x, wv.x, a);
        a = fmaf(xv.y, wv.y, a);
        a = fmaf(xv.z, wv.z, a);
        a = fmaf(xv.w, wv.w, a);
      }
    }
  }
  out[t] = (a > 0.f) ? a : 0.2f * a;
}

__global__ __launch_bounds__(256) void dec_s2(const float* __restrict__ in,
                                              const float* __restrict__ wt,
                                              const float* __restrict__ bs,
                                              float* __restrict__ out) {
  int t = blockIdx.x * 256 + threadIdx.x;
  int oc = t & 15, ox = (t >> 4) & 127, oy = (t >> 11) & 127, n = t >> 18;
  float a = bs[oc];
  int iyb = (oy - 2 + (oy & 1)) >> 1;
  int ixb = (ox - 2 + (ox & 1)) >> 1;
#pragma unroll
  for (int ay = 0; ay < 2; ++ay) {
    int iy = iyb + ay;
    if ((unsigned)iy >= 64u) continue;
    int ky = (oy & 1) + 2 * ay;
#pragma unroll
    for (int ax = 0; ax < 2; ++ax) {
      int ix = ixb + ax;
      if ((unsigned)ix >= 64u) continue;
      int kx = (ox & 1) + 2 * ax;
      const float4* xp = (const float4*)(in + ((n * 64 + iy) * 64 + ix) * 32);
      const float4* wp = (const float4*)(wt + ((ky * 4 + kx) * 16 + oc) * 32);
#pragma unroll
      for (int i4 = 0; i4 < 8; ++i4) {
        float4 xv = xp[i4], wv = wp[i4];
        a = fmaf(xv.x, wv.x, a);
        a = fmaf(xv.y, wv.y, a);
        a = fmaf(xv.z, wv.z, a);
        a = fmaf(xv.w, wv.w, a);
      }
    }
  }
  out[t] = (a > 0.f) ? a : 0.2f * a;
}

__global__ __launch_bounds__(256) void dec_s3(const float* __restrict__ in,
                                              const float* __restrict__ wt,
                                              const float* __restrict__ bs,
                                              float* __restrict__ out) {
  int t = blockIdx.x * 256 + threadIdx.x;
  int ox = t & 127, oy = (t >> 7) & 127, n = t >> 14;
  float a = bs[0];
#pragma unroll
  for (int ky = 0; ky < 3; ++ky) {
    int iy = oy + ky - 1;
    if ((unsigned)iy >= 128u) continue;
#pragma unroll
    for (int kx = 0; kx < 3; ++kx) {
      int ix = ox + kx - 1;
      if ((unsigned)ix >= 128u) continue;
      const float4* xp = (const float4*)(in + ((n * 128 + iy) * 128 + ix) * 16);
      const float4* wp = (const float4*)(wt + (ky * 3 + kx) * 16);
#pragma unroll
      for (int i4 = 0; i4 < 4; ++i4) {
        float4 xv = xp[i4], wv = wp[i4];
        a = fmaf(xv.x, wv.x, a);
        a = fmaf(xv.y, wv.y, a);
        a = fmaf(xv.z, wv.z, a);
        a = fmaf(xv.w, wv.w, a);
      }
    }
  }
  out[n * 16384 + oy * 128 + ox] = a;
}

// ---------------- host ----------------
extern "C" void kernel_launch(void* const* d_in, const int* in_sizes, int n_in,
                              void* d_out, int out_size, void* d_ws, size_t ws_size,
                              hipStream_t stream) {
  (void)in_sizes; (void)n_in; (void)out_size;
  (void)hipFuncSetAttribute((const void*)ode_persist,
                            hipFuncAttributeMaxDynamicSharedMemorySize, CONV_LDS);

  uint8_t* ws = (uint8_t*)d_ws;
  unsigned short* S0h = (unsigned short*)(ws + 0);
  unsigned short* S0l = (unsigned short*)(ws + 524288);
  unsigned short* S1h = (unsigned short*)(ws + 1048576);
  unsigned short* S1l = (unsigned short*)(ws + 1572864);
  unsigned short* T0h = (unsigned short*)(ws + 2097152);
  unsigned short* T0l = (unsigned short*)(ws + 2621440);
  unsigned short* T1h = (unsigned short*)(ws + 3145728);
  unsigned short* T1l = (unsigned short*)(ws + 3670016);
  unsigned short* WIMG = (unsigned short*)(ws + 5242880);
  float* s1wt = (float*)(ws + 5832704);
  float* s2wt = (float*)(ws + 5963776);
  float* s3wt = (float*)(ws + 5996544);
  int* progress = (int*)(ws + 6029312);       // 64 x int
  float* outs = (float*)(ws + 6291456);       // 10 x 262144 f32
  const size_t decBase = 16777216;

  const float* h_s0 = (const float*)d_in[0];
  const float* wode[4] = {(const float*)d_in[1], (const float*)d_in[3],
                          (const float*)d_in[5], (const float*)d_in[7]};
  const float* bode[4] = {(const float*)d_in[2], (const float*)d_in[4],
                          (const float*)d_in[6], (const float*)d_in[8]};
  const float* s1w = (const float*)d_in[9];
  const float* s1b = (const float*)d_in[10];
  const float* s2w = (const float*)d_in[11];
  const float* s2b = (const float*)d_in[12];
  const float* s3w = (const float*)d_in[13];
  const float* s3b = (const float*)d_in[14];

  (void)hipMemsetAsync(progress, 0, 64 * sizeof(int), stream);
  prep_weights<<<737, 256, 0, stream>>>(wode[0], wode[1], wode[2], wode[3],
                                        s1w, s2w, s3w, WIMG, s1wt, s2wt, s3wt);
  prep_state<<<1024, 256, 0, stream>>>(h_s0, S0h, S0l, outs);

  ode_persist<<<dim3(64), dim3(1024), CONV_LDS, stream>>>(
      WIMG, bode[0], bode[1], bode[2], bode[3],
      S0h, S0l, S1h, S1l, T0h, T0l, T1h, T1l, outs, progress);

  // decoder, chunked over timesteps to fit workspace
  size_t avail = (ws_size > decBase) ? (ws_size - decBase) : 0;
  int TCc = (int)(avail / 6291456ull);
  if (TCc < 1) TCc = 1;
  if (TCc > 10) TCc = 10;
  for (int t0 = 0; t0 < 10; t0 += TCc) {
    int tc = (TCc < 10 - t0) ? TCc : (10 - t0);
    int n = tc * 4;
    float* d1 = (float*)(ws + decBase);
    float* d2 = d1 + (size_t)n * 131072;      // n*64*64*32
    dec_s1<<<n * 512, 256, 0, stream>>>(outs + (size_t)t0 * 262144, s1wt, s1b, d1);
    dec_s2<<<n * 1024, 256, 0, stream>>>(d1, s2wt, s2b, d2);
    dec_s3<<<n * 64, 256, 0, stream>>>(d2, s3wt, s3b,
                                       (float*)d_out + (size_t)t0 * 65536);
  }
}

// Round 10
// 6393.130 us; speedup vs baseline: 1.0119x; 1.0119x over previous
//
#include <hip/hip_runtime.h>
#include <hip/hip_bf16.h>
#include <stdint.h>

typedef __attribute__((ext_vector_type(8))) short short8;
typedef __attribute__((ext_vector_type(4))) float f32x4;
typedef __attribute__((ext_vector_type(4))) int int4v;

__device__ __forceinline__ float bf2f(unsigned short u) {
  union { unsigned int i; float f; } v; v.i = ((unsigned int)u) << 16; return v.f;
}
__device__ __forceinline__ unsigned short f2bf(float f) {
  union { float f; unsigned int i; } v; v.f = f;
  unsigned int i = v.i;
  i += 0x7FFFu + ((i >> 16) & 1u);
  return (unsigned short)(i >> 16);
}
__device__ __forceinline__ float tanh_fast(float x) {
  float e = __expf(2.0f * x);
  return 1.0f - 2.0f / (e + 1.0f);
}

// ---------------- weight prep (same layouts as round 9) ----------------
__global__ void prep_weights(const float* __restrict__ w1, const float* __restrict__ w2,
                             const float* __restrict__ w3, const float* __restrict__ w4,
                             const float* __restrict__ s1w, const float* __restrict__ s2w,
                             const float* __restrict__ s3w,
                             unsigned short* __restrict__ wimg,
                             float* __restrict__ s1wt, float* __restrict__ s2wt,
                             float* __restrict__ s3wt) {
  int t = blockIdx.x * 256 + threadIdx.x;
  if (t < 147456) {
    int l = t / 36864;
    int oc = (t / 576) & 63;
    int ic = (t / 9) & 63;
    int tap = t % 9;
    const float* w = (l == 0) ? w1 : (l == 1) ? w2 : (l == 2) ? w3 : w4;
    float v = w[(oc * 64 + ic) * 9 + tap];
    unsigned short hi = f2bf(v);
    unsigned short lo = f2bf(v - bf2f(hi));
    int icb = ic >> 5, icm = ic & 31;
    int idx = (icb * 64 + oc) * 288 + tap * 32 + icm;
    wimg[l * 73728 + idx]         = hi;
    wimg[l * 73728 + 36864 + idx] = lo;
  } else if (t < 180224) {
    int u = t - 147456;                       // [kk][oc32][ic64]
    int ic = u & 63, oc = (u >> 6) & 31, kk = u >> 11;
    int ky = kk >> 2, kx = kk & 3;
    s1wt[u] = s1w[((oc * 64 + ic) * 4 + ky) * 4 + kx];
  } else if (t < 188416) {
    int u = t - 180224;                       // [kk][oc16][ic32]
    int ic = u & 31, oc = (u >> 5) & 15, kk = u >> 9;
    int ky = kk >> 2, kx = kk & 3;
    s2wt[u] = s2w[((oc * 32 + ic) * 4 + ky) * 4 + kx];
  } else if (t < 188560) {
    int u = t - 188416;                       // [kk][ic16]
    int ic = u & 15, kk = u >> 4;
    int ky = kk / 3, kx = kk % 3;
    s3wt[u] = s3w[ic * 9 + ky * 3 + kx];
  }
}

// NCHW h_s0 -> P3 pair + Yb f32 + outs[0]
__global__ void prep_state(const float* __restrict__ src,
                           unsigned short* __restrict__ p3h, unsigned short* __restrict__ p3l,
                           float* __restrict__ Yb, float* __restrict__ outs0) {
  int t = blockIdx.x * 256 + threadIdx.x;    // NHWC flat
  int c = t & 63, w = (t >> 6) & 31, h = (t >> 11) & 31, b = t >> 16;
  float v = src[((b * 64 + c) * 32 + h) * 32 + w];
  unsigned short hi = f2bf(v);
  p3h[t] = hi;
  p3l[t] = f2bf(v - bf2f(hi));
  Yb[t] = v;
  outs0[t] = v;
}

// ---------------- fused 2-conv group, persistent kernel ------------------------
// 64 blocks x 1024 thr. Group = {net layer 2g+1 -> LDS MID (tanh pair), net layer
// 2g+2 -> global}. IN: 6 rows pair (halo 2) staged from P[(G+3)&3]; out P[G&3].
// Layer A: 16 waves, task (ro 0..3, half, nt) = M16 x N32, out rows h0-1..h0+2.
// Layer B: 8 waves,  task (row2 0..1, half, nt) = M16 x N32, out rows h0..h0+1.
// Edge rows outside image are stored as ZERO in MID (conv zero-padding).
#define LDS_IN_ARR 29376
#define LDS_MID 58752
#define LDS_MID_ARR 19584
#define CONV_LDS 97920

__global__ __launch_bounds__(1024) void ode_persist(
    const unsigned short* __restrict__ wimg,
    const float* __restrict__ b1, const float* __restrict__ b2,
    const float* __restrict__ b3, const float* __restrict__ b4,
    unsigned short* __restrict__ P0h, unsigned short* __restrict__ P0l,
    unsigned short* __restrict__ P1h, unsigned short* __restrict__ P1l,
    unsigned short* __restrict__ P2h, unsigned short* __restrict__ P2l,
    unsigned short* __restrict__ P3h, unsigned short* __restrict__ P3l,
    float* __restrict__ Yb, float* __restrict__ Rb,
    float* __restrict__ outs, int* progress) {
  extern __shared__ uint8_t lds[];
  const int tid = threadIdx.x;
  const int blk = blockIdx.x;
  const int b = blk >> 4;
  const int rp = blk & 15;
  const int h0 = rp << 1;
  const int nbA = (rp > 0) ? blk - 1 : -1;
  const int nbB = (rp < 15) ? blk + 1 : -1;

  unsigned short* Ph[4] = {P0h, P1h, P2h, P3h};
  unsigned short* Pl[4] = {P0l, P1l, P2l, P3l};

  const int lane = tid & 63;
  const int wv = tid >> 6;
  const int lmod = lane & 15;
  const int lg = lane >> 4;
  const int nt = wv & 1;
  const int spA = wv >> 1;                    // 0..7
  const int roA = spA >> 1;                   // 0..3 (MID row)
  const int hfA = spA & 1;
  const int rwB = (wv >> 1) >> 1;             // valid when wv<8: 0..1
  const int hfB = (wv >> 1) & 1;

  // zero MID pad columns (w1 = 0, 33) once; they stay zero forever
  if (tid < 144) {
    int arr = tid / 72;
    int r2 = tid - arr * 72;
    int c = r2 % 9;
    int cr = r2 / 9;                          // [row4][col2]
    *(int4v*)(lds + LDS_MID + arr * LDS_MID_ARR +
              ((cr >> 1) * 34 + (cr & 1) * 33) * 144 + c * 16) = (int4v){0, 0, 0, 0};
  }

  int G = 0;
  for (int f = 0; f < 72; ++f) {
    const int sub = f & 3;
    const int stp = f >> 2;
    for (int ph = 0; ph < 2; ++ph, ++G) {
      const unsigned short* wA = wimg + (ph ? 2 : 0) * 73728;
      const unsigned short* wB = wimg + (ph ? 3 : 1) * 73728;
      const float* bsA = ph ? b3 : b1;
      const float* bsB = ph ? b4 : b2;
      const unsigned short* inHi = Ph[(G + 3) & 3];
      const unsigned short* inLo = Pl[(G + 3) & 3];
      unsigned short* outHi = Ph[G & 3];
      unsigned short* outLo = Pl[G & 3];
      const int mode = ph ? (1 + sub) : 0;
      float* op = (ph && sub == 3 && ((stp + 1) & 1) == 0)
                      ? outs + (size_t)((stp + 1) >> 1) * 262144 : nullptr;

      // ---- wait: neighbors completed >= G groups (halo inputs ready)
      if (tid == 0 && G > 0) {
        if (nbA >= 0)
          while (__hip_atomic_load(&progress[nbA], __ATOMIC_ACQUIRE,
                                   __HIP_MEMORY_SCOPE_AGENT) < G)
            __builtin_amdgcn_s_sleep(2);
        if (nbB >= 0)
          while (__hip_atomic_load(&progress[nbB], __ATOMIC_ACQUIRE,
                                   __HIP_MEMORY_SCOPE_AGENT) < G)
            __builtin_amdgcn_s_sleep(2);
        __threadfence();
      }
      __syncthreads();

      // ---- stage IN: rows h0-2..h0+3, pair, zero-padded
#pragma unroll
      for (int k = 0; k < 4; ++k) {
        int idx = tid + k * 1024;
        if (idx < 3264) {
          int arr = idx / 1632;
          int r2 = idx - arr * 1632;
          int c = r2 & 7;
          int w1 = (r2 >> 3) % 34;
          int row = (r2 >> 3) / 34;
          int hp = h0 - 2 + row;
          int w = w1 - 1;
          int4v v = {0, 0, 0, 0};
          if (hp >= 0 && hp < 32 && w >= 0 && w < 32)
            v = *(const int4v*)((arr ? inLo : inHi) + (((b * 32 + hp) * 32 + w) * 64 + c * 8));
          *(int4v*)(lds + arr * LDS_IN_ARR + (row * 34 + w1) * 144 + c * 16) = v;
        }
      }
      __syncthreads();

      // ---- layer A (net layer 1 or 3): 16 waves -> MID (tanh pair / zeros)
      {
        const int wo = (nt * 32 + lmod) * 288 + lg * 8;
        f32x4 acc0 = {0.f, 0.f, 0.f, 0.f}, acc1 = {0.f, 0.f, 0.f, 0.f};
        short8 bh0 = *(const short8*)(wA + wo);
        short8 bh1 = *(const short8*)(wA + wo + 4608);
        short8 bl0 = *(const short8*)(wA + wo + 36864);
        short8 bl1 = *(const short8*)(wA + wo + 41472);
#pragma unroll
        for (int s = 0; s < 18; ++s) {
          short8 nh0, nh1, nl0, nl1;
          if (s < 17) {
            const int s2 = s + 1, icb2 = (s2 >= 9) ? 1 : 0, tp2 = s2 - icb2 * 9;
            const int d = icb2 * 18432 + tp2 * 32;
            nh0 = *(const short8*)(wA + wo + d);
            nh1 = *(const short8*)(wA + wo + 4608 + d);
            nl0 = *(const short8*)(wA + wo + 36864 + d);
            nl1 = *(const short8*)(wA + wo + 41472 + d);
          }
          const int icb = (s >= 9) ? 1 : 0, tp = s - icb * 9;
          const int dy = tp / 3, dx = tp % 3;
          const int ab = ((roA + dy) * 34 + hfA * 16 + lmod + dx) * 144 + (icb * 4 + lg) * 16;
          short8 ah = *(const short8*)(lds + ab);
          short8 al = *(const short8*)(lds + LDS_IN_ARR + ab);
          acc0 = __builtin_amdgcn_mfma_f32_16x16x32_bf16(ah, bh0, acc0, 0, 0, 0);
          acc0 = __builtin_amdgcn_mfma_f32_16x16x32_bf16(al, bh0, acc0, 0, 0, 0);
          acc0 = __builtin_amdgcn_mfma_f32_16x16x32_bf16(ah, bl0, acc0, 0, 0, 0);
          acc1 = __builtin_amdgcn_mfma_f32_16x16x32_bf16(ah, bh1, acc1, 0, 0, 0);
          acc1 = __builtin_amdgcn_mfma_f32_16x16x32_bf16(al, bh1, acc1, 0, 0, 0);
          acc1 = __builtin_amdgcn_mfma_f32_16x16x32_bf16(ah, bl1, acc1, 0, 0, 0);
          if (s < 17) { bh0 = nh0; bh1 = nh1; bl0 = nl0; bl1 = nl1; }
        }
        const int hr = h0 - 1 + roA;
        const float inimg = ((unsigned)hr < 32u) ? 1.0f : 0.0f;   // zero padding rows
        const float bz0 = bsA[nt * 32 + lmod];
        const float bz1 = bsA[nt * 32 + 16 + lmod];
#pragma unroll
        for (int j = 0; j < 4; ++j) {
          const int px = hfA * 16 + lg * 4 + j;
          const int off = (roA * 34 + px + 1) * 144;
          float v0 = inimg * tanh_fast(acc0[j] + bz0);
          unsigned short h0v = f2bf(v0);
          *(unsigned short*)(lds + LDS_MID + off + (nt * 32 + lmod) * 2) = h0v;
          *(unsigned short*)(lds + LDS_MID + LDS_MID_ARR + off + (nt * 32 + lmod) * 2) =
              f2bf(v0 - bf2f(h0v));
          float v1 = inimg * tanh_fast(acc1[j] + bz1);
          unsigned short h1v = f2bf(v1);
          *(unsigned short*)(lds + LDS_MID + off + (nt * 32 + 16 + lmod) * 2) = h1v;
          *(unsigned short*)(lds + LDS_MID + LDS_MID_ARR + off + (nt * 32 + 16 + lmod) * 2) =
              f2bf(v1 - bf2f(h1v));
        }
      }
      __syncthreads();

      // ---- layer B (net layer 2 or 4): 8 waves -> global rows h0..h0+1
      if (wv < 8) {
        const int wo = (nt * 32 + lmod) * 288 + lg * 8;
        f32x4 acc0 = {0.f, 0.f, 0.f, 0.f}, acc1 = {0.f, 0.f, 0.f, 0.f};
        short8 bh0 = *(const short8*)(wB + wo);
        short8 bh1 = *(const short8*)(wB + wo + 4608);
        short8 bl0 = *(const short8*)(wB + wo + 36864);
        short8 bl1 = *(const short8*)(wB + wo + 41472);
#pragma unroll
        for (int s = 0; s < 18; ++s) {
          short8 nh0, nh1, nl0, nl1;
          if (s < 17) {
            const int s2 = s + 1, icb2 = (s2 >= 9) ? 1 : 0, tp2 = s2 - icb2 * 9;
            const int d = icb2 * 18432 + tp2 * 32;
            nh0 = *(const short8*)(wB + wo + d);
            nh1 = *(const short8*)(wB + wo + 4608 + d);
            nl0 = *(const short8*)(wB + wo + 36864 + d);
            nl1 = *(const short8*)(wB + wo + 41472 + d);
          }
          const int icb = (s >= 9) ? 1 : 0, tp = s - icb * 9;
          const int dy = tp / 3, dx = tp % 3;
          const int ab = LDS_MID + ((rwB + dy) * 34 + hfB * 16 + lmod + dx) * 144 +
                         (icb * 4 + lg) * 16;
          short8 ah = *(const short8*)(lds + ab);
          short8 al = *(const short8*)(lds + LDS_MID_ARR + ab);
          acc0 = __builtin_amdgcn_mfma_f32_16x16x32_bf16(ah, bh0, acc0, 0, 0, 0);
          acc0 = __builtin_amdgcn_mfma_f32_16x16x32_bf16(al, bh0, acc0, 0, 0, 0);
          acc0 = __builtin_amdgcn_mfma_f32_16x16x32_bf16(ah, bl0, acc0, 0, 0, 0);
          acc1 = __builtin_amdgcn_mfma_f32_16x16x32_bf16(ah, bh1, acc1, 0, 0, 0);
          acc1 = __builtin_amdgcn_mfma_f32_16x16x32_bf16(al, bh1, acc1, 0, 0, 0);
          acc1 = __builtin_amdgcn_mfma_f32_16x16x32_bf16(ah, bl1, acc1, 0, 0, 0);
          if (s < 17) { bh0 = nh0; bh1 = nh1; bl0 = nl0; bl1 = nl1; }
        }
        const int hr = h0 + rwB;
        const float bz0 = bsB[nt * 32 + lmod];
        const float bz1 = bsB[nt * 32 + 16 + lmod];
#pragma unroll
        for (int j = 0; j < 4; ++j) {
          const int px = hfB * 16 + lg * 4 + j;
#pragma unroll
          for (int ns = 0; ns < 2; ++ns) {
            const float kv = ns ? (acc1[j] + bz1) : (acc0[j] + bz0);
            const int oc = nt * 32 + ns * 16 + lmod;
            const int e = (b * 1024 + hr * 32 + px) * 64 + oc;
            if (mode == 0) {                  // tanh -> T2 pair
              float v = tanh_fast(kv);
              unsigned short hh = f2bf(v);
              outHi[e] = hh;
              outLo[e] = f2bf(v - bf2f(hh));
            } else if (mode == 1) {           // k1
              float y = Yb[e];
              float z = fmaf(0.25f, kv, y);
              Rb[e] = fmaf(1.0f / 12.0f, kv, y);
              unsigned short hh = f2bf(z);
              outHi[e] = hh;
              outLo[e] = f2bf(z - bf2f(hh));
            } else if (mode == 2 || mode == 3) {
              float y = Yb[e];
              float cz = (mode == 2) ? 0.25f : 0.5f;
              float z = fmaf(cz, kv, y);
              Rb[e] = fmaf(1.0f / 6.0f, kv, Rb[e]);
              unsigned short hh = f2bf(z);
              outHi[e] = hh;
              outLo[e] = f2bf(z - bf2f(hh));
            } else {                          // k4 -> new y
              float z = fmaf(1.0f / 12.0f, kv, Rb[e]);
              Yb[e] = z;
              unsigned short hh = f2bf(z);
              outHi[e] = hh;
              outLo[e] = f2bf(z - bf2f(hh));
              if (op) op[e] = z;
            }
          }
        }
      }
      __syncthreads();
      if (tid == 0) {
        __threadfence();
        __hip_atomic_store(&progress[blk], G + 1, __ATOMIC_RELEASE,
                           __HIP_MEMORY_SCOPE_AGENT);
      }
    }
  }
}

// ---------------- decoder (round-9 version, passing) ----------------
__global__ __launch_bounds__(256) void dec_s1(const float* __restrict__ in,
                                              const float* __restrict__ wt,
                                              const float* __restrict__ bs,
                                              float* __restrict__ out) {
  int t = blockIdx.x * 256 + threadIdx.x;
  int oc = t & 31, ox = (t >> 5) & 63, oy = (t >> 11) & 63, n = t >> 17;
  float a = bs[oc];
  int iyb = (oy - 2 + (oy & 1)) >> 1;
  int ixb = (ox - 2 + (ox & 1)) >> 1;
#pragma unroll
  for (int ay = 0; ay < 2; ++ay) {
    int iy = iyb + ay;
    if ((unsigned)iy >= 32u) continue;
    int ky = (oy & 1) + 2 * ay;
#pragma unroll
    for (int ax = 0; ax < 2; ++ax) {
      int ix = ixb + ax;
      if ((unsigned)ix >= 32u) continue;
      int kx = (ox & 1) + 2 * ax;
      const float4* xp = (const float4*)(in + ((n * 32 + iy) * 32 + ix) * 64);
      const float4* wp = (const float4*)(wt + ((ky * 4 + kx) * 32 + oc) * 64);
#pragma unroll
      for (int i4 = 0; i4 < 16; ++i4) {
        float4 xv = xp[i4], wv = wp[i4];
        a = fmaf(xv.x, wv.x, a);
        a = fmaf(xv.y, wv.y, a);
        a = fmaf(xv.z, wv.z, a);
        a = fmaf(xv.w, wv.w, a);
      }
    }
  }
  out[t] = (a > 0.f) ? a : 0.2f * a;
}

__global__ __launch_bounds__(256) void dec_s2(const float* __restrict__ in,
                                              const float* __restrict__ wt,
                                              const float* __restrict__ bs,
                                              float* __restrict__ out) {
  int t = blockIdx.x * 256 + threadIdx.x;
  int oc = t & 15, ox = (t >> 4) & 127, oy = (t >> 11) & 127, n = t >> 18;
  float a = bs[oc];
  int iyb = (oy - 2 + (oy & 1)) >> 1;
  int ixb = (ox - 2 + (ox & 1)) >> 1;
#pragma unroll
  for (int ay = 0; ay < 2; ++ay) {
    int iy = iyb + ay;
    if ((unsigned)iy >= 64u) continue;
    int ky = (oy & 1) + 2 * ay;
#pragma unroll
    for (int ax = 0; ax < 2; ++ax) {
      int ix = ixb + ax;
      if ((unsigned)ix >= 64u) continue;
      int kx = (ox & 1) + 2 * ax;
      const float4* xp = (const float4*)(in + ((n * 64 + iy) * 64 + ix) * 32);
      const float4* wp = (const float4*)(wt + ((ky * 4 + kx) * 16 + oc) * 32);
#pragma unroll
      for (int i4 = 0; i4 < 8; ++i4) {
        float4 xv = xp[i4], wv = wp[i4];
        a = fmaf(xv.x, wv.x, a);
        a = fmaf(xv.y, wv.y, a);
        a = fmaf(xv.z, wv.z, a);
        a = fmaf(xv.w, wv.w, a);
      }
    }
  }
  out[t] = (a > 0.f) ? a : 0.2f * a;
}

__global__ __launch_bounds__(256) void dec_s3(const float* __restrict__ in,
                                              const float* __restrict__ wt,
                                              const float* __restrict__ bs,
                                              float* __restrict__ out) {
  int t = blockIdx.x * 256 + threadIdx.x;
  int ox = t & 127, oy = (t >> 7) & 127, n = t >> 14;
  float a = bs[0];
#pragma unroll
  for (int ky = 0; ky < 3; ++ky) {
    int iy = oy + ky - 1;
    if ((unsigned)iy >= 128u) continue;
#pragma unroll
    for (int kx = 0; kx < 3; ++kx) {
      int ix = ox + kx - 1;
      if ((unsigned)ix >= 128u) continue;
      const float4* xp = (const float4*)(in + ((n * 128 + iy) * 128 + ix) * 16);
      const float4* wp = (const float4*)(wt + (ky * 3 + kx) * 16);
#pragma unroll
      for (int i4 = 0; i4 < 4; ++i4) {
        float4 xv = xp[i4], wv = wp[i4];
        a = fmaf(xv.x, wv.x, a);
        a = fmaf(xv.y, wv.y, a);
        a = fmaf(xv.z, wv.z, a);
        a = fmaf(xv.w, wv.w, a);
      }
    }
  }
  out[n * 16384 + oy * 128 + ox] = a;
}

// ---------------- host ----------------
extern "C" void kernel_launch(void* const* d_in, const int* in_sizes, int n_in,
                              void* d_out, int out_size, void* d_ws, size_t ws_size,
                              hipStream_t stream) {
  (void)in_sizes; (void)n_in; (void)out_size; (void)ws_size;
  (void)hipFuncSetAttribute((const void*)ode_persist,
                            hipFuncAttributeMaxDynamicSharedMemorySize, CONV_LDS);

  uint8_t* ws = (uint8_t*)d_ws;
  // P rotation pair buffers (dead after ODE; decoder scratch reuses [0, 6 MB))
  unsigned short* P0h = (unsigned short*)(ws + 0);
  unsigned short* P0l = (unsigned short*)(ws + 524288);
  unsigned short* P1h = (unsigned short*)(ws + 1048576);
  unsigned short* P1l = (unsigned short*)(ws + 1572864);
  unsigned short* P2h = (unsigned short*)(ws + 2097152);
  unsigned short* P2l = (unsigned short*)(ws + 2621440);
  unsigned short* P3h = (unsigned short*)(ws + 3145728);
  unsigned short* P3l = (unsigned short*)(ws + 3670016);
  float* Yb = (float*)(ws + 4194304);         // 1 MB
  float* Rb = (float*)(ws + 5242880);         // 1 MB
  unsigned short* WIMG = (unsigned short*)(ws + 6291456);   // 589824 B
  float* s1wt = (float*)(ws + 6881280);
  float* s2wt = (float*)(ws + 7012352);
  float* s3wt = (float*)(ws + 7045120);
  int* progress = (int*)(ws + 7077888);       // 64 x int
  float* outs = (float*)(ws + 7340032);       // 10 x 262144 f32 (survives decode)

  const float* h_s0 = (const float*)d_in[0];
  const float* wode[4] = {(const float*)d_in[1], (const float*)d_in[3],
                          (const float*)d_in[5], (const float*)d_in[7]};
  const float* bode[4] = {(const float*)d_in[2], (const float*)d_in[4],
                          (const float*)d_in[6], (const float*)d_in[8]};
  const float* s1w = (const float*)d_in[9];
  const float* s1b = (const float*)d_in[10];
  const float* s2w = (const float*)d_in[11];
  const float* s2b = (const float*)d_in[12];
  const float* s3w = (const float*)d_in[13];
  const float* s3b = (const float*)d_in[14];

  (void)hipMemsetAsync(progress, 0, 64 * sizeof(int), stream);
  prep_weights<<<737, 256, 0, stream>>>(wode[0], wode[1], wode[2], wode[3],
                                        s1w, s2w, s3w, WIMG, s1wt, s2wt, s3wt);
  prep_state<<<1024, 256, 0, stream>>>(h_s0, P3h, P3l, Yb, outs);

  ode_persist<<<dim3(64), dim3(1024), CONV_LDS, stream>>>(
      WIMG, bode[0], bode[1], bode[2], bode[3],
      P0h, P0l, P1h, P1l, P2h, P2l, P3h, P3l, Yb, Rb, outs, progress);

  // decoder: scratch reuses the (now dead) P/Yb/Rb region [0, 6 MB)
  for (int t0 = 0; t0 < 10; ++t0) {
    float* d1 = (float*)(ws + 0);             // 4*64*64*32 f32 = 2 MB
    float* d2 = (float*)(ws + 2097152);       // 4*128*128*16 f32 = 4 MB
    dec_s1<<<2048, 256, 0, stream>>>(outs + (size_t)t0 * 262144, s1wt, s1b, d1);
    dec_s2<<<4096, 256, 0, stream>>>(d1, s2wt, s2b, d2);
    dec_s3<<<256, 256, 0, stream>>>(d2, s3wt, s3b,
                                    (float*)d_out + (size_t)t0 * 65536);
  }
}

// Round 13
// 5107.565 us; speedup vs baseline: 1.2667x; 1.2517x over previous
//
#include <hip/hip_runtime.h>
#include <hip/hip_bf16.h>
#include <stdint.h>

typedef __attribute__((ext_vector_type(8))) short short8;
typedef __attribute__((ext_vector_type(4))) float f32x4;
typedef __attribute__((ext_vector_type(4))) int int4v;

__device__ __forceinline__ float bf2f(unsigned short u) {
  union { unsigned int i; float f; } v; v.i = ((unsigned int)u) << 16; return v.f;
}
__device__ __forceinline__ unsigned short f2bf(float f) {
  union { float f; unsigned int i; } v; v.f = f;
  unsigned int i = v.i;
  i += 0x7FFFu + ((i >> 16) & 1u);
  return (unsigned short)(i >> 16);
}
__device__ __forceinline__ float tanh_fast(float x) {
  float e = __expf(2.0f * x);
  return 1.0f - 2.0f / (e + 1.0f);
}
__device__ __forceinline__ uint32_t pack_pair(float v) {
  unsigned short hi = f2bf(v);
  unsigned short lo = f2bf(v - bf2f(hi));
  return (uint32_t)hi | ((uint32_t)lo << 16);
}

// ---------------- weight prep ----------------
// ODE: wimg[arr(hi/lo)][icb][oc][tap][icm] per layer (73728 elems/layer), bf16
// decoder (ic-contiguous): s1wt[kk][oc32][ic64], s2wt[kk][oc16][ic32], s3wt[kk][ic16]
__global__ void prep_weights(const float* __restrict__ w1, const float* __restrict__ w2,
                             const float* __restrict__ w3, const float* __restrict__ w4,
                             const float* __restrict__ s1w, const float* __restrict__ s2w,
                             const float* __restrict__ s3w,
                             unsigned short* __restrict__ wimg,
                             float* __restrict__ s1wt, float* __restrict__ s2wt,
                             float* __restrict__ s3wt) {
  int t = blockIdx.x * 256 + threadIdx.x;
  if (t < 147456) {
    int l = t / 36864;
    int oc = (t / 576) & 63;
    int ic = (t / 9) & 63;
    int tap = t % 9;
    const float* w = (l == 0) ? w1 : (l == 1) ? w2 : (l == 2) ? w3 : w4;
    float v = w[(oc * 64 + ic) * 9 + tap];
    unsigned short hi = f2bf(v);
    unsigned short lo = f2bf(v - bf2f(hi));
    int icb = ic >> 5, icm = ic & 31;
    int idx = (icb * 64 + oc) * 288 + tap * 32 + icm;
    wimg[l * 73728 + idx]         = hi;
    wimg[l * 73728 + 36864 + idx] = lo;
  } else if (t < 180224) {
    int u = t - 147456;                       // [kk][oc32][ic64]
    int ic = u & 63, oc = (u >> 6) & 31, kk = u >> 11;
    int ky = kk >> 2, kx = kk & 3;
    s1wt[u] = s1w[((oc * 64 + ic) * 4 + ky) * 4 + kx];
  } else if (t < 188416) {
    int u = t - 180224;                       // [kk][oc16][ic32]
    int ic = u & 31, oc = (u >> 5) & 15, kk = u >> 9;
    int ky = kk >> 2, kx = kk & 3;
    s2wt[u] = s2w[((oc * 32 + ic) * 4 + ky) * 4 + kx];
  } else if (t < 188560) {
    int u = t - 188416;                       // [kk][ic16]
    int ic = u & 15, kk = u >> 4;
    int ky = kk / 3, kx = kk % 3;
    s3wt[u] = s3w[ic * 9 + ky * 3 + kx];
  }
}

// NCHW h_s0 -> packed S0 + f32 outs[0]
__global__ void prep_state(const float* __restrict__ src,
                           uint32_t* __restrict__ s0, float* __restrict__ outs0) {
  int t = blockIdx.x * 256 + threadIdx.x;    // NHWC flat: ((b*32+h)*32+w)*64+c
  int c = t & 63, w = (t >> 6) & 31, h = (t >> 11) & 31, b = t >> 16;
  float v = src[((b * 64 + c) * 32 + h) * 32 + w];
  s0[t] = pack_pair(v);
  outs0[t] = v;
}

// ---------------- ODE conv body (1024 thr, 16 waves; wave = M16 x N16) --------
// LDS: A [arr2][row4][w34][144B] = 39168 B ; W (one icb) [arr2][oc64][624B] = 79872 B
// State in/out is PACKED uint32 (hi|lo<<16), moved with relaxed agent atomics
// (bypass L1/L2 to coherence point) => NO threadfence, W stays L2-cached.
#define LDS_A_ARR 19584
#define LDS_W_BASE 39168
#define LDS_W_ARR 39936
#define CONV_LDS 119040

__device__ __forceinline__ void conv_body(
    uint8_t* lds, int b, int h0,
    const uint32_t* __restrict__ inP,
    const unsigned short* __restrict__ wimg, const float* __restrict__ bias,
    uint32_t* __restrict__ outP,
    float* Y, float* R, float* __restrict__ outsPtr, int mode) {
  const int tid = threadIdx.x;

  // ---- stage A-tile: rows h0-1..h0+2, w1 0..33 padded; 8-ic chunks, unpack hi/lo
  for (int idx = tid; idx < 1088; idx += 1024) {
    int c = idx & 7;
    int w1 = (idx >> 3) % 34;
    int row = (idx >> 3) / 34;
    int hp = h0 - 1 + row;
    int w = w1 - 1;
    short8 hi8 = {0, 0, 0, 0, 0, 0, 0, 0};
    short8 lo8 = {0, 0, 0, 0, 0, 0, 0, 0};
    if (hp >= 0 && hp < 32 && w >= 0 && w < 32) {
      const uint32_t* sp = inP + (((b * 32 + hp) * 32 + w) * 64 + c * 8);
#pragma unroll
      for (int q = 0; q < 8; ++q) {
        uint32_t pk = __hip_atomic_load(sp + q, __ATOMIC_RELAXED,
                                        __HIP_MEMORY_SCOPE_AGENT);
        hi8[q] = (short)(pk & 0xFFFFu);
        lo8[q] = (short)(pk >> 16);
      }
    }
    const int off = (row * 34 + w1) * 144 + c * 16;
    *(short8*)(lds + off) = hi8;
    *(short8*)(lds + LDS_A_ARR + off) = lo8;
  }
  // ---- stage W icb=0 (plain cached loads; L2-hot) ; prefetch icb=1 into regs
  int4v wpre[5];
#pragma unroll
  for (int k = 0; k < 5; ++k) {
    int idx = tid + k * 1024;                 // 0..4607
    if (idx < 4608) {
      int arr = idx / 2304;
      int r2 = idx - arr * 2304;
      int oc = r2 / 36;
      int ch = r2 - oc * 36;
      int4v v0 = *(const int4v*)(wimg + (((arr * 2 + 0) * 64 + oc) * 288 + ch * 8));
      *(int4v*)(lds + LDS_W_BASE + (arr * 64 + oc) * 624 + ch * 16) = v0;
      wpre[k] = *(const int4v*)(wimg + (((arr * 2 + 1) * 64 + oc) * 288 + ch * 8));
    }
  }
  __syncthreads();

  const int lane = tid & 63;
  const int wv = tid >> 6;                    // 0..15
  const int mq = wv & 3;                      // M16 quarter
  const int ng = wv >> 2;                     // N16 group
  const int lmod = lane & 15;
  const int lg = lane >> 4;
  const int P = mq * 16 + lmod;               // A pixel (m = lane&15)
  const int r = P >> 5;
  const int c0 = P & 31;

  f32x4 acc = (f32x4){0.f, 0.f, 0.f, 0.f};

#pragma unroll
  for (int icb = 0; icb < 2; ++icb) {
    if (icb == 1) {
      __syncthreads();
#pragma unroll
      for (int k = 0; k < 5; ++k) {
        int idx = tid + k * 1024;
        if (idx < 4608) {
          int arr = idx / 2304;
          int r2 = idx - arr * 2304;
          int oc = r2 / 36;
          int ch = r2 - oc * 36;
          *(int4v*)(lds + LDS_W_BASE + (arr * 64 + oc) * 624 + ch * 16) = wpre[k];
        }
      }
      __syncthreads();
    }
#pragma unroll
    for (int tap = 0; tap < 9; ++tap) {
      const int dy = tap / 3, dx = tap % 3;
      const int abyte = ((r + dy) * 34 + (c0 + dx)) * 144 + (icb * 4 + lg) * 16;
      short8 ah = *(const short8*)(lds + abyte);
      short8 al = *(const short8*)(lds + abyte + LDS_A_ARR);
      const int wb = LDS_W_BASE + (ng * 16 + lmod) * 624 + tap * 64 + lg * 16;
      short8 bh = *(const short8*)(lds + wb);
      short8 bl = *(const short8*)(lds + wb + LDS_W_ARR);
      acc = __builtin_amdgcn_mfma_f32_16x16x32_bf16(ah, bh, acc, 0, 0, 0);
      acc = __builtin_amdgcn_mfma_f32_16x16x32_bf16(al, bh, acc, 0, 0, 0);
      acc = __builtin_amdgcn_mfma_f32_16x16x32_bf16(ah, bl, acc, 0, 0, 0);
    }
  }

  // ---- epilogue: D[m=(lane>>4)*4+j][n=lane&15]; oc = ng*16+n, px = mq*16+m
  const int oc = ng * 16 + lmod;
  const float bz = bias[oc];
#pragma unroll
  for (int j = 0; j < 4; ++j) {
    const int Pp = mq * 16 + lg * 4 + j;
    const int e = (b * 1024 + h0 * 32 + Pp) * 64 + oc;
    float kv = acc[j] + bz;
    float z;
    if (mode == 0) {                          // conv + tanh
      z = tanh_fast(kv);
    } else if (mode == 1) {                   // k1: z=y+0.25k ; R=y+k/12
      z = fmaf(0.25f, kv, Y[j]);
      R[j] = fmaf(1.0f / 12.0f, kv, Y[j]);
    } else if (mode == 2 || mode == 3) {      // k2/k3
      float cz = (mode == 2) ? 0.25f : 0.5f;
      z = fmaf(cz, kv, Y[j]);
      R[j] = fmaf(1.0f / 6.0f, kv, R[j]);
    } else {                                  // k4: ynew = R + k/12
      z = fmaf(1.0f / 12.0f, kv, R[j]);
      Y[j] = z;
      if (outsPtr) outsPtr[e] = z;
    }
    __hip_atomic_store(&outP[e], pack_pair(z), __ATOMIC_RELAXED,
                       __HIP_MEMORY_SCOPE_AGENT);
  }
}

// ---------------- persistent ODE kernel: 64 blocks x 16 waves, neighbor-sync ---
// grid 64 = 4 batch x 16 row-pairs; 1 block/CU, 4 waves/SIMD.
// progress[blk] = convs completed (RELEASE store after barrier drains all sc
// stores to the coherence point). Waiters spin with RELAXED loads (no L2 inv).
// Lockstep bound: block starts conv j only when neighbors completed j =>
// co-executing blocks are always at the SAME conv index; every conv's write
// buffer != read buffer (S->T0->T1->T0->S) => no RAW/WAR races.
__global__ __launch_bounds__(1024) void ode_persist(
    const unsigned short* __restrict__ wimg,
    const float* __restrict__ b1, const float* __restrict__ b2,
    const float* __restrict__ b3, const float* __restrict__ b4,
    uint32_t* __restrict__ S0, uint32_t* __restrict__ S1,
    uint32_t* __restrict__ T0, uint32_t* __restrict__ T1,
    float* __restrict__ outs, int* progress) {
  extern __shared__ uint8_t lds[];
  const int blk = blockIdx.x;
  const int b = blk >> 4;
  const int rp = blk & 15;
  const int h0 = rp << 1;
  const int nbA = (rp > 0) ? blk - 1 : -1;
  const int nbB = (rp < 15) ? blk + 1 : -1;

  const unsigned short* Wl[4] = {wimg, wimg + 73728, wimg + 147456, wimg + 221184};
  const float* Bl[4] = {b1, b2, b3, b4};

  // per-thread RK4 state: 4 outputs at (px = mq*16+lg*4+j, oc = ng*16+lmod)
  const int lane = threadIdx.x & 63;
  const int wv = threadIdx.x >> 6;
  const int mq = wv & 3, ng = wv >> 2;
  const int lmod = lane & 15, lg = lane >> 4;
  float Y[4], R[4];
#pragma unroll
  for (int j = 0; j < 4; ++j) {
    const int e = (b * 1024 + h0 * 32 + mq * 16 + lg * 4 + j) * 64 + ng * 16 + lmod;
    Y[j] = outs[e];                           // exact f32 initial state
    R[j] = 0.f;
  }

  int done = 0;
  for (int step = 1; step <= 18; ++step) {
    for (int sub = 0; sub < 4; ++sub) {
      for (int layer = 0; layer < 4; ++layer) {
        const uint32_t* inP;
        uint32_t* outP;
        int mode;
        float* op = nullptr;
        if (layer == 0) {
          inP = (sub == 0) ? S0 : S1; outP = T0; mode = 0;
        } else if (layer == 1) {
          inP = T0; outP = T1; mode = 0;
        } else if (layer == 2) {
          inP = T1; outP = T0; mode = 0;
        } else {
          inP = T0; outP = (sub == 3) ? S0 : S1; mode = 1 + sub;
          if (sub == 3 && (step & 1) == 0) op = outs + (size_t)(step >> 1) * 262144;
        }
        if (threadIdx.x == 0 && done > 0) {
          if (nbA >= 0)
            while (__hip_atomic_load(&progress[nbA], __ATOMIC_RELAXED,
                                     __HIP_MEMORY_SCOPE_AGENT) < done)
              __builtin_amdgcn_s_sleep(2);
          if (nbB >= 0)
            while (__hip_atomic_load(&progress[nbB], __ATOMIC_RELAXED,
                                     __HIP_MEMORY_SCOPE_AGENT) < done)
              __builtin_amdgcn_s_sleep(2);
        }
        __builtin_amdgcn_sched_barrier(0);
        __syncthreads();

        conv_body(lds, b, h0, inP, Wl[layer], Bl[layer], outP, Y, R, op, mode);

        __syncthreads();                      // drains all waves' stores (vmcnt)
        ++done;
        if (threadIdx.x == 0) {
          __hip_atomic_store(&progress[blk], done, __ATOMIC_RELEASE,
                             __HIP_MEMORY_SCOPE_AGENT);
        }
      }
    }
  }
}

// ---------------- decoder (fp32, parity-direct taps, float4 loads) --------------
__global__ __launch_bounds__(256) void dec_s1(const float* __restrict__ in,
                                              const float* __restrict__ wt,
                                              const float* __restrict__ bs,
                                              float* __restrict__ out) {
  int t = blockIdx.x * 256 + threadIdx.x;
  int oc = t & 31, ox = (t >> 5) & 63, oy = (t >> 11) & 63, n = t >> 17;
  float a = bs[oc];
  int iyb = (oy - 2 + (oy & 1)) >> 1;
  int ixb = (ox - 2 + (ox & 1)) >> 1;
#pragma unroll
  for (int ay = 0; ay < 2; ++ay) {
    int iy = iyb + ay;
    if ((unsigned)iy >= 32u) continue;
    int ky = (oy & 1) + 2 * ay;
#pragma unroll
    for (int ax = 0; ax < 2; ++ax) {
      int ix = ixb + ax;
      if ((unsigned)ix >= 32u) continue;
      int kx = (ox & 1) + 2 * ax;
      const float4* xp = (const float4*)(in + ((n * 32 + iy) * 32 + ix) * 64);
      const float4* wp = (const float4*)(wt + ((ky * 4 + kx) * 32 + oc) * 64);
#pragma unroll
      for (int i4 = 0; i4 < 16; ++i4) {
        float4 xv = xp[i4], wv = wp[i4];
        a = fmaf(xv.x, wv.x, a);
        a = fmaf(xv.y, wv.y, a);
        a = fmaf(xv.z, wv.z, a);
        a = fmaf(xv.w, wv.w, a);
      }
    }
  }
  out[t] = (a > 0.f) ? a : 0.2f * a;
}

__global__ __launch_bounds__(256) void dec_s2(const float* __restrict__ in,
                                              const float* __restrict__ wt,
                                              const float* __restrict__ bs,
                                              float* __restrict__ out) {
  int t = blockIdx.x * 256 + threadIdx.x;
  int oc = t & 15, ox = (t >> 4) & 127, oy = (t >> 11) & 127, n = t >> 18;
  float a = bs[oc];
  int iyb = (oy - 2 + (oy & 1)) >> 1;
  int ixb = (ox - 2 + (ox & 1)) >> 1;
#pragma unroll
  for (int ay = 0; ay < 2; ++ay) {
    int iy = iyb + ay;
    if ((unsigned)iy >= 64u) continue;
    int ky = (oy & 1) + 2 * ay;
#pragma unroll
    for (int ax = 0; ax < 2; ++ax) {
      int ix = ixb + ax;
      if ((unsigned)ix >= 64u) continue;
      int kx = (ox & 1) + 2 * ax;
      const float4* xp = (const float4*)(in + ((n * 64 + iy) * 64 + ix) * 32);
      const float4* wp = (const float4*)(wt + ((ky * 4 + kx) * 16 + oc) * 32);
#pragma unroll
      for (int i4 = 0; i4 < 8; ++i4) {
        float4 xv = xp[i4], wv = wp[i4];
        a = fmaf(xv.x, wv.x, a);
        a = fmaf(xv.y, wv.y, a);
        a = fmaf(xv.z, wv.z, a);
        a = fmaf(xv.w, wv.w, a);
      }
    }
  }
  out[t] = (a > 0.f) ? a : 0.2f * a;
}

__global__ __launch_bounds__(256) void dec_s3(const float* __restrict__ in,
                                              const float* __restrict__ wt,
                                              const float* __restrict__ bs,
                                              float* __restrict__ out) {
  int t = blockIdx.x * 256 + threadIdx.x;
  int ox = t & 127, oy = (t >> 7) & 127, n = t >> 14;
  float a = bs[0];
#pragma unroll
  for (int ky = 0; ky < 3; ++ky) {
    int iy = oy + ky - 1;
    if ((unsigned)iy >= 128u) continue;
#pragma unroll
    for (int kx = 0; kx < 3; ++kx) {
      int ix = ox + kx - 1;
      if ((unsigned)ix >= 128u) continue;
      const float4* xp = (const float4*)(in + ((n * 128 + iy) * 128 + ix) * 16);
      const float4* wp = (const float4*)(wt + (ky * 3 + kx) * 16);
#pragma unroll
      for (int i4 = 0; i4 < 4; ++i4) {
        float4 xv = xp[i4], wv = wp[i4];
        a = fmaf(xv.x, wv.x, a);
        a = fmaf(xv.y, wv.y, a);
        a = fmaf(xv.z, wv.z, a);
        a = fmaf(xv.w, wv.w, a);
      }
    }
  }
  out[n * 16384 + oy * 128 + ox] = a;
}

// ---------------- host ----------------
extern "C" void kernel_launch(void* const* d_in, const int* in_sizes, int n_in,
                              void* d_out, int out_size, void* d_ws, size_t ws_size,
                              hipStream_t stream) {
  (void)in_sizes; (void)n_in; (void)out_size; (void)ws_size;
  (void)hipFuncSetAttribute((const void*)ode_persist,
                            hipFuncAttributeMaxDynamicSharedMemorySize, CONV_LDS);

  uint8_t* ws = (uint8_t*)d_ws;
  uint32_t* S0 = (uint32_t*)(ws + 0);         // packed state, 1 MB each
  uint32_t* S1 = (uint32_t*)(ws + 1048576);
  uint32_t* T0 = (uint32_t*)(ws + 2097152);
  uint32_t* T1 = (uint32_t*)(ws + 3145728);
  unsigned short* WIMG = (unsigned short*)(ws + 4194304);   // 589824 B
  float* s1wt = (float*)(ws + 4784128);
  float* s2wt = (float*)(ws + 4915200);
  float* s3wt = (float*)(ws + 4947968);
  int* progress = (int*)(ws + 4980736);       // 64 x int
  float* outs = (float*)(ws + 5242880);       // 10 x 262144 f32
  float* d1 = (float*)(ws + 16777216);        // decoder scratch 2 MB
  float* d2 = (float*)(ws + 18874368);        // decoder scratch 4 MB

  const float* h_s0 = (const float*)d_in[0];
  const float* wode[4] = {(const float*)d_in[1], (const float*)d_in[3],
                          (const float*)d_in[5], (const float*)d_in[7]};
  const float* bode[4] = {(const float*)d_in[2], (const float*)d_in[4],
                          (const float*)d_in[6], (const float*)d_in[8]};
  const float* s1w = (const float*)d_in[9];
  const float* s1b = (const float*)d_in[10];
  const float* s2w = (const float*)d_in[11];
  const float* s2b = (const float*)d_in[12];
  const float* s3w = (const float*)d_in[13];
  const float* s3b = (const float*)d_in[14];

  (void)hipMemsetAsync(progress, 0, 64 * sizeof(int), stream);
  prep_weights<<<737, 256, 0, stream>>>(wode[0], wode[1], wode[2], wode[3],
                                        s1w, s2w, s3w, WIMG, s1wt, s2wt, s3wt);
  prep_state<<<1024, 256, 0, stream>>>(h_s0, S0, outs);

  ode_persist<<<dim3(64), dim3(1024), CONV_LDS, stream>>>(
      WIMG, bode[0], bode[1], bode[2], bode[3],
      S0, S1, T0, T1, outs, progress);

  for (int t0 = 0; t0 < 10; ++t0) {
    dec_s1<<<2048, 256, 0, stream>>>(outs + (size_t)t0 * 262144, s1wt, s1b, d1);
    dec_s2<<<4096, 256, 0, stream>>>(d1, s2wt, s2b, d2);
    dec_s3<<<256, 256, 0, stream>>>(d2, s3wt, s3b,
                                    (float*)d_out + (size_t)t0 * 65536);
  }
}

// Round 14
// 3717.298 us; speedup vs baseline: 1.7404x; 1.3740x over previous
//
#include <hip/hip_runtime.h>
#include <hip/hip_bf16.h>
#include <stdint.h>

typedef __attribute__((ext_vector_type(8))) short short8;
typedef __attribute__((ext_vector_type(4))) float f32x4;
typedef __attribute__((ext_vector_type(4))) int int4v;

__device__ __forceinline__ float bf2f(unsigned short u) {
  union { unsigned int i; float f; } v; v.i = ((unsigned int)u) << 16; return v.f;
}
__device__ __forceinline__ unsigned short f2bf(float f) {
  union { float f; unsigned int i; } v; v.f = f;
  unsigned int i = v.i;
  i += 0x7FFFu + ((i >> 16) & 1u);
  return (unsigned short)(i >> 16);
}
__device__ __forceinline__ float tanh_fast(float x) {
  float e = __expf(2.0f * x);
  return 1.0f - 2.0f / (e + 1.0f);
}
__device__ __forceinline__ uint32_t pack_pair(float v) {
  unsigned short hi = f2bf(v);
  unsigned short lo = f2bf(v - bf2f(hi));
  return (uint32_t)hi | ((uint32_t)lo << 16);
}

// ---------------- weight prep ----------------
// ODE: wimg[arr(hi/lo)][icb][oc][tap][icm] per layer (73728 elems/layer), bf16
// decoder (ic-contiguous): s1wt[kk][oc32][ic64], s2wt[kk][oc16][ic32], s3wt[kk][ic16]
__global__ void prep_weights(const float* __restrict__ w1, const float* __restrict__ w2,
                             const float* __restrict__ w3, const float* __restrict__ w4,
                             const float* __restrict__ s1w, const float* __restrict__ s2w,
                             const float* __restrict__ s3w,
                             unsigned short* __restrict__ wimg,
                             float* __restrict__ s1wt, float* __restrict__ s2wt,
                             float* __restrict__ s3wt) {
  int t = blockIdx.x * 256 + threadIdx.x;
  if (t < 147456) {
    int l = t / 36864;
    int oc = (t / 576) & 63;
    int ic = (t / 9) & 63;
    int tap = t % 9;
    const float* w = (l == 0) ? w1 : (l == 1) ? w2 : (l == 2) ? w3 : w4;
    float v = w[(oc * 64 + ic) * 9 + tap];
    unsigned short hi = f2bf(v);
    unsigned short lo = f2bf(v - bf2f(hi));
    int icb = ic >> 5, icm = ic & 31;
    int idx = (icb * 64 + oc) * 288 + tap * 32 + icm;
    wimg[l * 73728 + idx]         = hi;
    wimg[l * 73728 + 36864 + idx] = lo;
  } else if (t < 180224) {
    int u = t - 147456;                       // [kk][oc32][ic64]
    int ic = u & 63, oc = (u >> 6) & 31, kk = u >> 11;
    int ky = kk >> 2, kx = kk & 3;
    s1wt[u] = s1w[((oc * 64 + ic) * 4 + ky) * 4 + kx];
  } else if (t < 188416) {
    int u = t - 180224;                       // [kk][oc16][ic32]
    int ic = u & 31, oc = (u >> 5) & 15, kk = u >> 9;
    int ky = kk >> 2, kx = kk & 3;
    s2wt[u] = s2w[((oc * 32 + ic) * 4 + ky) * 4 + kx];
  } else if (t < 188560) {
    int u = t - 188416;                       // [kk][ic16]
    int ic = u & 15, kk = u >> 4;
    int ky = kk / 3, kx = kk % 3;
    s3wt[u] = s3w[ic * 9 + ky * 3 + kx];
  }
}

// NCHW h_s0 -> packed S0 + f32 outs[0]
__global__ void prep_state(const float* __restrict__ src,
                           uint32_t* __restrict__ s0, float* __restrict__ outs0) {
  int t = blockIdx.x * 256 + threadIdx.x;    // NHWC flat: ((b*32+h)*32+w)*64+c
  int c = t & 63, w = (t >> 6) & 31, h = (t >> 11) & 31, b = t >> 16;
  float v = src[((b * 64 + c) * 32 + h) * 32 + w];
  s0[t] = pack_pair(v);
  outs0[t] = v;
}

// ---------------- ODE conv body (1024 thr, 16 waves; wave = M16 x N16) --------
// LDS (XOR-swizzled, bank-conflict-free):
//   A[2 buf][arr2][pix136][chunk8]x16B : entry = buf*34816 + arr*17408 +
//       pix*128 + ((chunk ^ (pix&7))*16)            -> 69632 B
//   W[arr2][oc64][slot40]x16B          : entry = WBASE + arr*40960 +
//       oc*640 + ((slot ^ (oc&7))*16), slot = tap*4+icpart  -> 81920 B
// State handoff: packed uint32, relaxed agent atomics (IC), NO fences.
// Own output rows are written into A[next] in LDS at epilogue; only the 2
// halo rows are staged from IC each conv.
#define A_BUF 34816
#define A_ARR 17408
#define WBASE 69632
#define W_ARR 40960
#define CONV_LDS 151552

__device__ __forceinline__ void conv_body(
    uint8_t* lds, int b, int h0, int cur, int full,
    const uint32_t* __restrict__ inP,
    const unsigned short* __restrict__ wimg, const float* __restrict__ bias,
    uint32_t* __restrict__ outP,
    float* Y, float* R, float* __restrict__ outsPtr, int mode) {
  const int tid = threadIdx.x;
  uint8_t* A = lds + cur * A_BUF;
  uint8_t* An = lds + (cur ^ 1) * A_BUF;

  // ---- stage A rows from IC: full (4 rows, first conv) or halo rows {0,3}
  const int nitems = full ? 1088 : 544;
  for (int idx = tid; idx < nitems; idx += 1024) {
    int c = idx & 7;
    int w1 = (idx >> 3) % 34;
    int rsel = (idx >> 3) / 34;
    int row = full ? rsel : rsel * 3;         // halo: rows 0 and 3
    int hp = h0 - 1 + row;
    int w = w1 - 1;
    short8 hi8 = {0, 0, 0, 0, 0, 0, 0, 0};
    short8 lo8 = {0, 0, 0, 0, 0, 0, 0, 0};
    if (hp >= 0 && hp < 32 && w >= 0 && w < 32) {
      const uint64_t* sp = (const uint64_t*)(inP + (((b * 32 + hp) * 32 + w) * 64 + c * 8));
#pragma unroll
      for (int q = 0; q < 4; ++q) {
        uint64_t pk2 = __hip_atomic_load(sp + q, __ATOMIC_RELAXED,
                                         __HIP_MEMORY_SCOPE_AGENT);
        uint32_t p0 = (uint32_t)pk2, p1 = (uint32_t)(pk2 >> 32);
        hi8[q * 2]     = (short)(p0 & 0xFFFFu);
        lo8[q * 2]     = (short)(p0 >> 16);
        hi8[q * 2 + 1] = (short)(p1 & 0xFFFFu);
        lo8[q * 2 + 1] = (short)(p1 >> 16);
      }
    }
    const int pix = row * 34 + w1;
    const int off = pix * 128 + ((c ^ (pix & 7)) * 16);
    *(short8*)(A + off) = hi8;
    *(short8*)(A + A_ARR + off) = lo8;
  }
  // ---- stage W icb=0 ; prefetch icb=1 into regs (write after phase-0 compute)
  int4v wpre[5];
#pragma unroll
  for (int k = 0; k < 5; ++k) {
    int idx = tid + k * 1024;                 // 0..4607
    if (idx < 4608) {
      int arr = idx / 2304;
      int r2 = idx - arr * 2304;
      int oc = r2 / 36;
      int ch = r2 - oc * 36;
      int4v v0 = *(const int4v*)(wimg + (((arr * 2 + 0) * 64 + oc) * 288 + ch * 8));
      *(int4v*)(lds + WBASE + arr * W_ARR + oc * 640 + ((ch ^ (oc & 7)) * 16)) = v0;
      wpre[k] = *(const int4v*)(wimg + (((arr * 2 + 1) * 64 + oc) * 288 + ch * 8));
    }
  }
  __syncthreads();

  const int lane = tid & 63;
  const int wv = tid >> 6;                    // 0..15
  const int mq = wv & 3;                      // M16 quarter
  const int ng = wv >> 2;                     // N16 group
  const int lmod = lane & 15;
  const int lg = lane >> 4;
  const int P = mq * 16 + lmod;               // A pixel (m = lane&15)
  const int r = P >> 5;
  const int c0 = P & 31;
  const int oc = ng * 16 + lmod;

  f32x4 acc = (f32x4){0.f, 0.f, 0.f, 0.f};

#pragma unroll
  for (int icb = 0; icb < 2; ++icb) {
    if (icb == 1) {
      __syncthreads();
#pragma unroll
      for (int k = 0; k < 5; ++k) {
        int idx = tid + k * 1024;
        if (idx < 4608) {
          int arr = idx / 2304;
          int r2 = idx - arr * 2304;
          int oco = r2 / 36;
          int ch = r2 - oco * 36;
          *(int4v*)(lds + WBASE + arr * W_ARR + oco * 640 + ((ch ^ (oco & 7)) * 16)) = wpre[k];
        }
      }
      __syncthreads();
    }
#pragma unroll
    for (int tap = 0; tap < 9; ++tap) {
      const int dy = tap / 3, dx = tap % 3;
      const int pix = (r + dy) * 34 + (c0 + dx);
      const int chunk = icb * 4 + lg;
      const int abyte = pix * 128 + ((chunk ^ (pix & 7)) * 16);
      short8 ah = *(const short8*)(A + abyte);
      short8 al = *(const short8*)(A + A_ARR + abyte);
      const int slot = tap * 4 + lg;
      const int wb = WBASE + oc * 640 + ((slot ^ (oc & 7)) * 16);
      short8 bh = *(const short8*)(lds + wb);
      short8 bl = *(const short8*)(lds + wb + W_ARR);
      acc = __builtin_amdgcn_mfma_f32_16x16x32_bf16(ah, bh, acc, 0, 0, 0);
      acc = __builtin_amdgcn_mfma_f32_16x16x32_bf16(al, bh, acc, 0, 0, 0);
      acc = __builtin_amdgcn_mfma_f32_16x16x32_bf16(ah, bl, acc, 0, 0, 0);
    }
  }

  // ---- epilogue: D[m=(lane>>4)*4+j][n=lane&15]; px = mq*16+m, oc = ng*16+n
  //      write z: packed -> global (for neighbor halo) AND own rows -> A[next]
  const float bz = bias[oc];
#pragma unroll
  for (int j = 0; j < 4; ++j) {
    const int px = mq * 16 + lg * 4 + j;
    const int e = (b * 1024 + h0 * 32 + px) * 64 + oc;
    float kv = acc[j] + bz;
    float z;
    if (mode == 0) {                          // conv + tanh
      z = tanh_fast(kv);
    } else if (mode == 1) {                   // k1: z=y+0.25k ; R=y+k/12
      z = fmaf(0.25f, kv, Y[j]);
      R[j] = fmaf(1.0f / 12.0f, kv, Y[j]);
    } else if (mode == 2 || mode == 3) {      // k2/k3
      float cz = (mode == 2) ? 0.25f : 0.5f;
      z = fmaf(cz, kv, Y[j]);
      R[j] = fmaf(1.0f / 6.0f, kv, R[j]);
    } else {                                  // k4: ynew = R + k/12
      z = fmaf(1.0f / 12.0f, kv, R[j]);
      Y[j] = z;
      if (outsPtr) outsPtr[e] = z;
    }
    uint32_t pk = pack_pair(z);
    __hip_atomic_store(&outP[e], pk, __ATOMIC_RELAXED, __HIP_MEMORY_SCOPE_AGENT);
    // own rows into A[next]: tile row = 1 + (px>>5), w1 = (px&31)+1
    const int pix = (1 + (px >> 5)) * 34 + (px & 31) + 1;
    const int off = pix * 128 + (((oc >> 3) ^ (pix & 7)) * 16) + (oc & 7) * 2;
    *(unsigned short*)(An + off)         = (unsigned short)(pk & 0xFFFFu);
    *(unsigned short*)(An + A_ARR + off) = (unsigned short)(pk >> 16);
  }
}

// ---------------- persistent ODE kernel: 64 blocks x 16 waves, neighbor-sync ---
// grid 64 = 4 batch x 16 row-pairs; 1 block/CU, 4 waves/SIMD.
// progress[blk] = convs completed (RELEASE after barrier drains stores to IC).
// Waiters spin with RELAXED loads. Lockstep bound: co-executing blocks are at
// the SAME conv index; write buffer != read buffer (S->T0->T1->T0->S).
__global__ __launch_bounds__(1024) void ode_persist(
    const unsigned short* __restrict__ wimg,
    const float* __restrict__ b1, const float* __restrict__ b2,
    const float* __restrict__ b3, const float* __restrict__ b4,
    uint32_t* __restrict__ S0, uint32_t* __restrict__ S1,
    uint32_t* __restrict__ T0, uint32_t* __restrict__ T1,
    float* __restrict__ outs, int* progress) {
  extern __shared__ uint8_t lds[];
  const int blk = blockIdx.x;
  const int b = blk >> 4;
  const int rp = blk & 15;
  const int h0 = rp << 1;
  const int nbA = (rp > 0) ? blk - 1 : -1;
  const int nbB = (rp < 15) ? blk + 1 : -1;

  const unsigned short* Wl[4] = {wimg, wimg + 73728, wimg + 147456, wimg + 221184};
  const float* Bl[4] = {b1, b2, b3, b4};

  // zero the pad columns (w1 = 0, 33) of epilogue-written rows 1,2 in BOTH
  // A buffers (they are never re-staged nor epilogue-written; stay zero).
  if (threadIdx.x < 128) {
    int t = threadIdx.x;
    int chunk = t & 7;
    int col = ((t >> 3) & 1) * 33;
    int row = 1 + ((t >> 4) & 1);
    int arr = (t >> 5) & 1;
    int buf = (t >> 6) & 1;
    int pix = row * 34 + col;
    *(int4v*)(lds + buf * A_BUF + arr * A_ARR + pix * 128 +
              ((chunk ^ (pix & 7)) * 16)) = (int4v){0, 0, 0, 0};
  }
  __syncthreads();

  // per-thread RK4 state: 4 outputs at (px = mq*16+lg*4+j, oc = ng*16+lmod)
  const int lane = threadIdx.x & 63;
  const int wv = threadIdx.x >> 6;
  const int mq = wv & 3, ng = wv >> 2;
  const int lmod = lane & 15, lg = lane >> 4;
  float Y[4], R[4];
#pragma unroll
  for (int j = 0; j < 4; ++j) {
    const int e = (b * 1024 + h0 * 32 + mq * 16 + lg * 4 + j) * 64 + ng * 16 + lmod;
    Y[j] = outs[e];                           // exact f32 initial state
    R[j] = 0.f;
  }

  int done = 0;
  int cur = 0;
  for (int step = 1; step <= 18; ++step) {
    for (int sub = 0; sub < 4; ++sub) {
      for (int layer = 0; layer < 4; ++layer) {
        const uint32_t* inP;
        uint32_t* outP;
        int mode;
        float* op = nullptr;
        if (layer == 0) {
          inP = (sub == 0) ? S0 : S1; outP = T0; mode = 0;
        } else if (layer == 1) {
          inP = T0; outP = T1; mode = 0;
        } else if (layer == 2) {
          inP = T1; outP = T0; mode = 0;
        } else {
          inP = T0; outP = (sub == 3) ? S0 : S1; mode = 1 + sub;
          if (sub == 3 && (step & 1) == 0) op = outs + (size_t)(step >> 1) * 262144;
        }
        if (threadIdx.x == 0 && done > 0) {
          if (nbA >= 0)
            while (__hip_atomic_load(&progress[nbA], __ATOMIC_RELAXED,
                                     __HIP_MEMORY_SCOPE_AGENT) < done)
              __builtin_amdgcn_s_sleep(2);
          if (nbB >= 0)
            while (__hip_atomic_load(&progress[nbB], __ATOMIC_RELAXED,
                                     __HIP_MEMORY_SCOPE_AGENT) < done)
              __builtin_amdgcn_s_sleep(2);
        }
        __builtin_amdgcn_sched_barrier(0);
        __syncthreads();

        conv_body(lds, b, h0, cur, done == 0, inP, Wl[layer], Bl[layer], outP,
                  Y, R, op, mode);

        __syncthreads();                      // drains all waves' stores (vmcnt)
        ++done;
        cur ^= 1;
        if (threadIdx.x == 0) {
          __hip_atomic_store(&progress[blk], done, __ATOMIC_RELEASE,
                             __HIP_MEMORY_SCOPE_AGENT);
        }
      }
    }
  }
}

// ---------------- decoder (fp32, parity-direct taps, float4 loads) --------------
__global__ __launch_bounds__(256) void dec_s1(const float* __restrict__ in,
                                              const float* __restrict__ wt,
                                              const float* __restrict__ bs,
                                              float* __restrict__ out) {
  int t = blockIdx.x * 256 + threadIdx.x;
  int oc = t & 31, ox = (t >> 5) & 63, oy = (t >> 11) & 63, n = t >> 17;
  float a = bs[oc];
  int iyb = (oy - 2 + (oy & 1)) >> 1;
  int ixb = (ox - 2 + (ox & 1)) >> 1;
#pragma unroll
  for (int ay = 0; ay < 2; ++ay) {
    int iy = iyb + ay;
    if ((unsigned)iy >= 32u) continue;
    int ky = (oy & 1) + 2 * ay;
#pragma unroll
    for (int ax = 0; ax < 2; ++ax) {
      int ix = ixb + ax;
      if ((unsigned)ix >= 32u) continue;
      int kx = (ox & 1) + 2 * ax;
      const float4* xp = (const float4*)(in + ((n * 32 + iy) * 32 + ix) * 64);
      const float4* wp = (const float4*)(wt + ((ky * 4 + kx) * 32 + oc) * 64);
#pragma unroll
      for (int i4 = 0; i4 < 16; ++i4) {
        float4 xv = xp[i4], wv = wp[i4];
        a = fmaf(xv.x, wv.x, a);
        a = fmaf(xv.y, wv.y, a);
        a = fmaf(xv.z, wv.z, a);
        a = fmaf(xv.w, wv.w, a);
      }
    }
  }
  out[t] = (a > 0.f) ? a : 0.2f * a;
}

__global__ __launch_bounds__(256) void dec_s2(const float* __restrict__ in,
                                              const float* __restrict__ wt,
                                              const float* __restrict__ bs,
                                              float* __restrict__ out) {
  int t = blockIdx.x * 256 + threadIdx.x;
  int oc = t & 15, ox = (t >> 4) & 127, oy = (t >> 11) & 127, n = t >> 18;
  float a = bs[oc];
  int iyb = (oy - 2 + (oy & 1)) >> 1;
  int ixb = (ox - 2 + (ox & 1)) >> 1;
#pragma unroll
  for (int ay = 0; ay < 2; ++ay) {
    int iy = iyb + ay;
    if ((unsigned)iy >= 64u) continue;
    int ky = (oy & 1) + 2 * ay;
#pragma unroll
    for (int ax = 0; ax < 2; ++ax) {
      int ix = ixb + ax;
      if ((unsigned)ix >= 64u) continue;
      int kx = (ox & 1) + 2 * ax;
      const float4* xp = (const float4*)(in + ((n * 64 + iy) * 64 + ix) * 32);
      const float4* wp = (const float4*)(wt + ((ky * 4 + kx) * 16 + oc) * 32);
#pragma unroll
      for (int i4 = 0; i4 < 8; ++i4) {
        float4 xv = xp[i4], wv = wp[i4];
        a = fmaf(xv.x, wv.x, a);
        a = fmaf(xv.y, wv.y, a);
        a = fmaf(xv.z, wv.z, a);
        a = fmaf(xv.w, wv.w, a);
      }
    }
  }
  out[t] = (a > 0.f) ? a : 0.2f * a;
}

__global__ __launch_bounds__(256) void dec_s3(const float* __restrict__ in,
                                              const float* __restrict__ wt,
                                              const float* __restrict__ bs,
                                              float* __restrict__ out) {
  int t = blockIdx.x * 256 + threadIdx.x;
  int ox = t & 127, oy = (t >> 7) & 127, n = t >> 14;
  float a = bs[0];
#pragma unroll
  for (int ky = 0; ky < 3; ++ky) {
    int iy = oy + ky - 1;
    if ((unsigned)iy >= 128u) continue;
#pragma unroll
    for (int kx = 0; kx < 3; ++kx) {
      int ix = ox + kx - 1;
      if ((unsigned)ix >= 128u) continue;
      const float4* xp = (const float4*)(in + ((n * 128 + iy) * 128 + ix) * 16);
      const float4* wp = (const float4*)(wt + (ky * 3 + kx) * 16);
#pragma unroll
      for (int i4 = 0; i4 < 4; ++i4) {
        float4 xv = xp[i4], wv = wp[i4];
        a = fmaf(xv.x, wv.x, a);
        a = fmaf(xv.y, wv.y, a);
        a = fmaf(xv.z, wv.z, a);
        a = fmaf(xv.w, wv.w, a);
      }
    }
  }
  out[n * 16384 + oy * 128 + ox] = a;
}

// ---------------- host ----------------
extern "C" void kernel_launch(void* const* d_in, const int* in_sizes, int n_in,
                              void* d_out, int out_size, void* d_ws, size_t ws_size,
                              hipStream_t stream) {
  (void)in_sizes; (void)n_in; (void)out_size; (void)ws_size;
  (void)hipFuncSetAttribute((const void*)ode_persist,
                            hipFuncAttributeMaxDynamicSharedMemorySize, CONV_LDS);

  uint8_t* ws = (uint8_t*)d_ws;
  uint32_t* S0 = (uint32_t*)(ws + 0);         // packed state, 1 MB each
  uint32_t* S1 = (uint32_t*)(ws + 1048576);
  uint32_t* T0 = (uint32_t*)(ws + 2097152);
  uint32_t* T1 = (uint32_t*)(ws + 3145728);
  unsigned short* WIMG = (unsigned short*)(ws + 4194304);   // 589824 B
  float* s1wt = (float*)(ws + 4784128);
  float* s2wt = (float*)(ws + 4915200);
  float* s3wt = (float*)(ws + 4947968);
  int* progress = (int*)(ws + 4980736);       // 64 x int
  float* outs = (float*)(ws + 5242880);       // 10 x 262144 f32
  float* d1 = (float*)(ws + 16777216);        // decoder scratch 2 MB
  float* d2 = (float*)(ws + 18874368);        // decoder scratch 4 MB

  const float* h_s0 = (const float*)d_in[0];
  const float* wode[4] = {(const float*)d_in[1], (const float*)d_in[3],
                          (const float*)d_in[5], (const float*)d_in[7]};
  const float* bode[4] = {(const float*)d_in[2], (const float*)d_in[4],
                          (const float*)d_in[6], (const float*)d_in[8]};
  const float* s1w = (const float*)d_in[9];
  const float* s1b = (const float*)d_in[10];
  const float* s2w = (const float*)d_in[11];
  const float* s2b = (const float*)d_in[12];
  const float* s3w = (const float*)d_in[13];
  const float* s3b = (const float*)d_in[14];

  (void)hipMemsetAsync(progress, 0, 64 * sizeof(int), stream);
  prep_weights<<<737, 256, 0, stream>>>(wode[0], wode[1], wode[2], wode[3],
                                        s1w, s2w, s3w, WIMG, s1wt, s2wt, s3wt);
  prep_state<<<1024, 256, 0, stream>>>(h_s0, S0, outs);

  ode_persist<<<dim3(64), dim3(1024), CONV_LDS, stream>>>(
      WIMG, bode[0], bode[1], bode[2], bode[3],
      S0, S1, T0, T1, outs, progress);

  for (int t0 = 0; t0 < 10; ++t0) {
    dec_s1<<<2048, 256, 0, stream>>>(outs + (size_t)t0 * 262144, s1wt, s1b, d1);
    dec_s2<<<4096, 256, 0, stream>>>(d1, s2wt, s2b, d2);
    dec_s3<<<256, 256, 0, stream>>>(d2, s3wt, s3b,
                                    (float*)d_out + (size_t)t0 * 65536);
  }
}

// Round 15
// 2673.974 us; speedup vs baseline: 2.4194x; 1.3902x over previous
//
#include <hip/hip_runtime.h>
#include <hip/hip_bf16.h>
#include <stdint.h>

typedef __attribute__((ext_vector_type(8))) short short8;
typedef __attribute__((ext_vector_type(4))) float f32x4;
typedef __attribute__((ext_vector_type(4))) int int4v;

__device__ __forceinline__ float bf2f(unsigned short u) {
  union { unsigned int i; float f; } v; v.i = ((unsigned int)u) << 16; return v.f;
}
__device__ __forceinline__ unsigned short f2bf(float f) {
  union { float f; unsigned int i; } v; v.f = f;
  unsigned int i = v.i;
  i += 0x7FFFu + ((i >> 16) & 1u);
  return (unsigned short)(i >> 16);
}
__device__ __forceinline__ float tanh_fast(float x) {
  float e = __expf(2.0f * x);
  return 1.0f - 2.0f / (e + 1.0f);
}
__device__ __forceinline__ uint32_t pack_pair(float v) {
  unsigned short hi = f2bf(v);
  unsigned short lo = f2bf(v - bf2f(hi));
  return (uint32_t)hi | ((uint32_t)lo << 16);
}

// ---------------- weight prep ----------------
// ODE: wimg[arr(hi/lo)][icb][oc][tap][icm] per layer (73728 elems/layer), bf16
// decoder (oc-contiguous): s1wt[kk][ic64][oc32], s2wt[kk][ic32][oc16], s3wt[kk][ic16]
__global__ void prep_weights(const float* __restrict__ w1, const float* __restrict__ w2,
                             const float* __restrict__ w3, const float* __restrict__ w4,
                             const float* __restrict__ s1w, const float* __restrict__ s2w,
                             const float* __restrict__ s3w,
                             unsigned short* __restrict__ wimg,
                             float* __restrict__ s1wt, float* __restrict__ s2wt,
                             float* __restrict__ s3wt) {
  int t = blockIdx.x * 256 + threadIdx.x;
  if (t < 147456) {
    int l = t / 36864;
    int oc = (t / 576) & 63;
    int ic = (t / 9) & 63;
    int tap = t % 9;
    const float* w = (l == 0) ? w1 : (l == 1) ? w2 : (l == 2) ? w3 : w4;
    float v = w[(oc * 64 + ic) * 9 + tap];
    unsigned short hi = f2bf(v);
    unsigned short lo = f2bf(v - bf2f(hi));
    int icb = ic >> 5, icm = ic & 31;
    int idx = (icb * 64 + oc) * 288 + tap * 32 + icm;
    wimg[l * 73728 + idx]         = hi;
    wimg[l * 73728 + 36864 + idx] = lo;
  } else if (t < 180224) {
    int u = t - 147456;                       // -> s1wt[(kk*64+ic)*32+oc]
    int oc = u & 31, ic = (u >> 5) & 63, kk = u >> 11;
    int ky = kk >> 2, kx = kk & 3;
    s1wt[(kk * 64 + ic) * 32 + oc] = s1w[((oc * 64 + ic) * 4 + ky) * 4 + kx];
  } else if (t < 188416) {
    int u = t - 180224;                       // -> s2wt[(kk*32+ic)*16+oc]
    int oc = u & 15, ic = (u >> 4) & 31, kk = u >> 9;
    int ky = kk >> 2, kx = kk & 3;
    s2wt[(kk * 32 + ic) * 16 + oc] = s2w[((oc * 32 + ic) * 4 + ky) * 4 + kx];
  } else if (t < 188560) {
    int u = t - 188416;                       // [kk][ic16]
    int ic = u & 15, kk = u >> 4;
    int ky = kk / 3, kx = kk % 3;
    s3wt[u] = s3w[ic * 9 + ky * 3 + kx];
  }
}

// NCHW h_s0 -> packed S0 + f32 outs[0]
__global__ void prep_state(const float* __restrict__ src,
                           uint32_t* __restrict__ s0, float* __restrict__ outs0) {
  int t = blockIdx.x * 256 + threadIdx.x;    // NHWC flat: ((b*32+h)*32+w)*64+c
  int c = t & 63, w = (t >> 6) & 31, h = (t >> 11) & 31, b = t >> 16;
  float v = src[((b * 64 + c) * 32 + h) * 32 + w];
  s0[t] = pack_pair(v);
  outs0[t] = v;
}

// ---------------- ODE conv body (1024 thr, 16 waves; wave = M16 x N16) --------
// LDS (XOR-swizzled, bank-conflict-free):
//   A[2 buf][arr2][pix136][chunk8]x16B : entry = buf*34816 + arr*17408 +
//       pix*128 + ((chunk ^ (pix&7))*16)            -> 69632 B
//   W[arr2][oc64][slot40]x16B          : entry = WBASE + arr*40960 +
//       oc*640 + ((slot ^ (oc&7))*16), slot = tap*4+icpart  -> 81920 B
// State handoff: packed uint32, relaxed agent atomics (IC), NO fences.
// Own output rows are written into A[next] in LDS at epilogue; only the 2
// halo rows are staged from IC each conv.
#define A_BUF 34816
#define A_ARR 17408
#define WBASE 69632
#define W_ARR 40960
#define CONV_LDS 151552

__device__ __forceinline__ void conv_body(
    uint8_t* lds, int b, int h0, int cur, int full,
    const uint32_t* __restrict__ inP,
    const unsigned short* __restrict__ wimg, const float* __restrict__ bias,
    uint32_t* __restrict__ outP,
    float* Y, float* R, float* __restrict__ outsPtr, int mode) {
  const int tid = threadIdx.x;
  uint8_t* A = lds + cur * A_BUF;
  uint8_t* An = lds + (cur ^ 1) * A_BUF;

  // ---- stage A rows from IC: full (4 rows, first conv) or halo rows {0,3}
  const int nitems = full ? 1088 : 544;
  for (int idx = tid; idx < nitems; idx += 1024) {
    int c = idx & 7;
    int w1 = (idx >> 3) % 34;
    int rsel = (idx >> 3) / 34;
    int row = full ? rsel : rsel * 3;         // halo: rows 0 and 3
    int hp = h0 - 1 + row;
    int w = w1 - 1;
    short8 hi8 = {0, 0, 0, 0, 0, 0, 0, 0};
    short8 lo8 = {0, 0, 0, 0, 0, 0, 0, 0};
    if (hp >= 0 && hp < 32 && w >= 0 && w < 32) {
      const uint64_t* sp = (const uint64_t*)(inP + (((b * 32 + hp) * 32 + w) * 64 + c * 8));
#pragma unroll
      for (int q = 0; q < 4; ++q) {
        uint64_t pk2 = __hip_atomic_load(sp + q, __ATOMIC_RELAXED,
                                         __HIP_MEMORY_SCOPE_AGENT);
        uint32_t p0 = (uint32_t)pk2, p1 = (uint32_t)(pk2 >> 32);
        hi8[q * 2]     = (short)(p0 & 0xFFFFu);
        lo8[q * 2]     = (short)(p0 >> 16);
        hi8[q * 2 + 1] = (short)(p1 & 0xFFFFu);
        lo8[q * 2 + 1] = (short)(p1 >> 16);
      }
    }
    const int pix = row * 34 + w1;
    const int off = pix * 128 + ((c ^ (pix & 7)) * 16);
    *(short8*)(A + off) = hi8;
    *(short8*)(A + A_ARR + off) = lo8;
  }
  // ---- stage W icb=0 ; prefetch icb=1 into regs (write after phase-0 compute)
  int4v wpre[5];
#pragma unroll
  for (int k = 0; k < 5; ++k) {
    int idx = tid + k * 1024;                 // 0..4607
    if (idx < 4608) {
      int arr = idx / 2304;
      int r2 = idx - arr * 2304;
      int oc = r2 / 36;
      int ch = r2 - oc * 36;
      int4v v0 = *(const int4v*)(wimg + (((arr * 2 + 0) * 64 + oc) * 288 + ch * 8));
      *(int4v*)(lds + WBASE + arr * W_ARR + oc * 640 + ((ch ^ (oc & 7)) * 16)) = v0;
      wpre[k] = *(const int4v*)(wimg + (((arr * 2 + 1) * 64 + oc) * 288 + ch * 8));
    }
  }
  __syncthreads();

  const int lane = tid & 63;
  const int wv = tid >> 6;                    // 0..15
  const int mq = wv & 3;                      // M16 quarter
  const int ng = wv >> 2;                     // N16 group
  const int lmod = lane & 15;
  const int lg = lane >> 4;
  const int P = mq * 16 + lmod;               // A pixel (m = lane&15)
  const int r = P >> 5;
  const int c0 = P & 31;
  const int oc = ng * 16 + lmod;

  f32x4 acc = (f32x4){0.f, 0.f, 0.f, 0.f};

#pragma unroll
  for (int icb = 0; icb < 2; ++icb) {
    if (icb == 1) {
      __syncthreads();
#pragma unroll
      for (int k = 0; k < 5; ++k) {
        int idx = tid + k * 1024;
        if (idx < 4608) {
          int arr = idx / 2304;
          int r2 = idx - arr * 2304;
          int oco = r2 / 36;
          int ch = r2 - oco * 36;
          *(int4v*)(lds + WBASE + arr * W_ARR + oco * 640 + ((ch ^ (oco & 7)) * 16)) = wpre[k];
        }
      }
      __syncthreads();
    }
#pragma unroll
    for (int tap = 0; tap < 9; ++tap) {
      const int dy = tap / 3, dx = tap % 3;
      const int pix = (r + dy) * 34 + (c0 + dx);
      const int chunk = icb * 4 + lg;
      const int abyte = pix * 128 + ((chunk ^ (pix & 7)) * 16);
      short8 ah = *(const short8*)(A + abyte);
      short8 al = *(const short8*)(A + A_ARR + abyte);
      const int slot = tap * 4 + lg;
      const int wb = WBASE + oc * 640 + ((slot ^ (oc & 7)) * 16);
      short8 bh = *(const short8*)(lds + wb);
      short8 bl = *(const short8*)(lds + wb + W_ARR);
      acc = __builtin_amdgcn_mfma_f32_16x16x32_bf16(ah, bh, acc, 0, 0, 0);
      acc = __builtin_amdgcn_mfma_f32_16x16x32_bf16(al, bh, acc, 0, 0, 0);
      acc = __builtin_amdgcn_mfma_f32_16x16x32_bf16(ah, bl, acc, 0, 0, 0);
    }
  }

  // ---- epilogue: D[m=(lane>>4)*4+j][n=lane&15]; px = mq*16+m, oc = ng*16+n
  //      write z: packed -> global (for neighbor halo) AND own rows -> A[next]
  const float bz = bias[oc];
#pragma unroll
  for (int j = 0; j < 4; ++j) {
    const int px = mq * 16 + lg * 4 + j;
    const int e = (b * 1024 + h0 * 32 + px) * 64 + oc;
    float kv = acc[j] + bz;
    float z;
    if (mode == 0) {                          // conv + tanh
      z = tanh_fast(kv);
    } else if (mode == 1) {                   // k1: z=y+0.25k ; R=y+k/12
      z = fmaf(0.25f, kv, Y[j]);
      R[j] = fmaf(1.0f / 12.0f, kv, Y[j]);
    } else if (mode == 2 || mode == 3) {      // k2/k3
      float cz = (mode == 2) ? 0.25f : 0.5f;
      z = fmaf(cz, kv, Y[j]);
      R[j] = fmaf(1.0f / 6.0f, kv, R[j]);
    } else {                                  // k4: ynew = R + k/12
      z = fmaf(1.0f / 12.0f, kv, R[j]);
      Y[j] = z;
      if (outsPtr) outsPtr[e] = z;
    }
    uint32_t pk = pack_pair(z);
    __hip_atomic_store(&outP[e], pk, __ATOMIC_RELAXED, __HIP_MEMORY_SCOPE_AGENT);
    // own rows into A[next]: tile row = 1 + (px>>5), w1 = (px&31)+1
    const int pix = (1 + (px >> 5)) * 34 + (px & 31) + 1;
    const int off = pix * 128 + (((oc >> 3) ^ (pix & 7)) * 16) + (oc & 7) * 2;
    *(unsigned short*)(An + off)         = (unsigned short)(pk & 0xFFFFu);
    *(unsigned short*)(An + A_ARR + off) = (unsigned short)(pk >> 16);
  }
}

// ---------------- persistent ODE kernel: 64 blocks x 16 waves, neighbor-sync ---
// grid 64 = 4 batch x 16 row-pairs; 1 block/CU, 4 waves/SIMD.
// progress[blk] = convs completed (RELEASE after barrier drains stores to IC).
// Waiters spin with RELAXED loads. Lockstep bound: co-executing blocks are at
// the SAME conv index; write buffer != read buffer (S->T0->T1->T0->S).
__global__ __launch_bounds__(1024) void ode_persist(
    const unsigned short* __restrict__ wimg,
    const float* __restrict__ b1, const float* __restrict__ b2,
    const float* __restrict__ b3, const float* __restrict__ b4,
    uint32_t* __restrict__ S0, uint32_t* __restrict__ S1,
    uint32_t* __restrict__ T0, uint32_t* __restrict__ T1,
    float* __restrict__ outs, int* progress) {
  extern __shared__ uint8_t lds[];
  const int blk = blockIdx.x;
  const int b = blk >> 4;
  const int rp = blk & 15;
  const int h0 = rp << 1;
  const int nbA = (rp > 0) ? blk - 1 : -1;
  const int nbB = (rp < 15) ? blk + 1 : -1;

  const unsigned short* Wl[4] = {wimg, wimg + 73728, wimg + 147456, wimg + 221184};
  const float* Bl[4] = {b1, b2, b3, b4};

  // zero the pad columns (w1 = 0, 33) of epilogue-written rows 1,2 in BOTH
  // A buffers (they are never re-staged nor epilogue-written; stay zero).
  if (threadIdx.x < 128) {
    int t = threadIdx.x;
    int chunk = t & 7;
    int col = ((t >> 3) & 1) * 33;
    int row = 1 + ((t >> 4) & 1);
    int arr = (t >> 5) & 1;
    int buf = (t >> 6) & 1;
    int pix = row * 34 + col;
    *(int4v*)(lds + buf * A_BUF + arr * A_ARR + pix * 128 +
              ((chunk ^ (pix & 7)) * 16)) = (int4v){0, 0, 0, 0};
  }
  __syncthreads();

  // per-thread RK4 state: 4 outputs at (px = mq*16+lg*4+j, oc = ng*16+lmod)
  const int lane = threadIdx.x & 63;
  const int wv = threadIdx.x >> 6;
  const int mq = wv & 3, ng = wv >> 2;
  const int lmod = lane & 15, lg = lane >> 4;
  float Y[4], R[4];
#pragma unroll
  for (int j = 0; j < 4; ++j) {
    const int e = (b * 1024 + h0 * 32 + mq * 16 + lg * 4 + j) * 64 + ng * 16 + lmod;
    Y[j] = outs[e];                           // exact f32 initial state
    R[j] = 0.f;
  }

  int done = 0;
  int cur = 0;
  for (int step = 1; step <= 18; ++step) {
    for (int sub = 0; sub < 4; ++sub) {
      for (int layer = 0; layer < 4; ++layer) {
        const uint32_t* inP;
        uint32_t* outP;
        int mode;
        float* op = nullptr;
        if (layer == 0) {
          inP = (sub == 0) ? S0 : S1; outP = T0; mode = 0;
        } else if (layer == 1) {
          inP = T0; outP = T1; mode = 0;
        } else if (layer == 2) {
          inP = T1; outP = T0; mode = 0;
        } else {
          inP = T0; outP = (sub == 3) ? S0 : S1; mode = 1 + sub;
          if (sub == 3 && (step & 1) == 0) op = outs + (size_t)(step >> 1) * 262144;
        }
        if (threadIdx.x == 0 && done > 0) {
          if (nbA >= 0)
            while (__hip_atomic_load(&progress[nbA], __ATOMIC_RELAXED,
                                     __HIP_MEMORY_SCOPE_AGENT) < done)
              __builtin_amdgcn_s_sleep(2);
          if (nbB >= 0)
            while (__hip_atomic_load(&progress[nbB], __ATOMIC_RELAXED,
                                     __HIP_MEMORY_SCOPE_AGENT) < done)
              __builtin_amdgcn_s_sleep(2);
        }
        __builtin_amdgcn_sched_barrier(0);
        __syncthreads();

        conv_body(lds, b, h0, cur, done == 0, inP, Wl[layer], Bl[layer], outP,
                  Y, R, op, mode);

        __syncthreads();                      // drains all waves' stores (vmcnt)
        ++done;
        cur ^= 1;
        if (threadIdx.x == 0) {
          __hip_atomic_store(&progress[blk], done, __ATOMIC_RELEASE,
                             __HIP_MEMORY_SCOPE_AGENT);
        }
      }
    }
  }
}

// ---------------- decoder: parity-specialized blocks, LDS weights -------------
// dec_s1: grid = img4 x parity4 x 128 ; block 256 = 8 pos x 32 oc ; wl 32KB
__global__ __launch_bounds__(256) void dec_s1(const float* __restrict__ in,
                                              const float* __restrict__ wt,
                                              const float* __restrict__ bs,
                                              float* __restrict__ out) {
  __shared__ float wl[4][64][32];
  const int tid = threadIdx.x;
  const int bl = blockIdx.x & 127;
  const int par = (blockIdx.x >> 7) & 3;
  const int n = blockIdx.x >> 9;
  const int py = par >> 1, px = par & 1;
#pragma unroll
  for (int k = 0; k < 32; ++k) {
    int s = tid + k * 256;                    // 0..8191
    int oc_ = s & 31, ic = (s >> 5) & 63, tp = s >> 11;
    int kk = (py + 2 * (tp >> 1)) * 4 + (px + 2 * (tp & 1));
    wl[tp][ic][oc_] = wt[(kk * 64 + ic) * 32 + oc_];
  }
  __syncthreads();
  const int oc = tid & 31;
  const int pos = bl * 8 + (tid >> 5);
  const int my = pos >> 5, mx = pos & 31;
  float a = bs[oc];
#pragma unroll
  for (int ay = 0; ay < 2; ++ay) {
    int iy = my + py - 1 + ay;
    if ((unsigned)iy >= 32u) continue;
#pragma unroll
    for (int ax = 0; ax < 2; ++ax) {
      int ix = mx + px - 1 + ax;
      if ((unsigned)ix >= 32u) continue;
      const float4* xp = (const float4*)(in + ((n * 32 + iy) * 32 + ix) * 64);
      const int tp = ay * 2 + ax;
#pragma unroll
      for (int i4 = 0; i4 < 16; ++i4) {
        float4 xv = xp[i4];
        a = fmaf(xv.x, wl[tp][i4 * 4 + 0][oc], a);
        a = fmaf(xv.y, wl[tp][i4 * 4 + 1][oc], a);
        a = fmaf(xv.z, wl[tp][i4 * 4 + 2][oc], a);
        a = fmaf(xv.w, wl[tp][i4 * 4 + 3][oc], a);
      }
    }
  }
  const int oy = 2 * my + py, ox = 2 * mx + px;
  out[((n * 64 + oy) * 64 + ox) * 32 + oc] = (a > 0.f) ? a : 0.2f * a;
}

// dec_s2: grid = img4 x parity4 x 256 ; block 256 = 16 pos x 16 oc ; wl 8KB
__global__ __launch_bounds__(256) void dec_s2(const float* __restrict__ in,
                                              const float* __restrict__ wt,
                                              const float* __restrict__ bs,
                                              float* __restrict__ out) {
  __shared__ float wl[4][32][16];
  const int tid = threadIdx.x;
  const int bl = blockIdx.x & 255;
  const int par = (blockIdx.x >> 8) & 3;
  const int n = blockIdx.x >> 10;
  const int py = par >> 1, px = par & 1;
#pragma unroll
  for (int k = 0; k < 8; ++k) {
    int s = tid + k * 256;                    // 0..2047
    int oc_ = s & 15, ic = (s >> 4) & 31, tp = s >> 9;
    int kk = (py + 2 * (tp >> 1)) * 4 + (px + 2 * (tp & 1));
    wl[tp][ic][oc_] = wt[(kk * 32 + ic) * 16 + oc_];
  }
  __syncthreads();
  const int oc = tid & 15;
  const int pos = bl * 16 + (tid >> 4);
  const int my = pos >> 6, mx = pos & 63;
  float a = bs[oc];
#pragma unroll
  for (int ay = 0; ay < 2; ++ay) {
    int iy = my + py - 1 + ay;
    if ((unsigned)iy >= 64u) continue;
#pragma unroll
    for (int ax = 0; ax < 2; ++ax) {
      int ix = mx + px - 1 + ax;
      if ((unsigned)ix >= 64u) continue;
      const float4* xp = (const float4*)(in + ((n * 64 + iy) * 64 + ix) * 32);
      const int tp = ay * 2 + ax;
#pragma unroll
      for (int i4 = 0; i4 < 8; ++i4) {
        float4 xv = xp[i4];
        a = fmaf(xv.x, wl[tp][i4 * 4 + 0][oc], a);
        a = fmaf(xv.y, wl[tp][i4 * 4 + 1][oc], a);
        a = fmaf(xv.z, wl[tp][i4 * 4 + 2][oc], a);
        a = fmaf(xv.w, wl[tp][i4 * 4 + 3][oc], a);
      }
    }
  }
  const int oy = 2 * my + py, ox = 2 * mx + px;
  out[((n * 128 + oy) * 128 + ox) * 16 + oc] = (a > 0.f) ? a : 0.2f * a;
}

__global__ __launch_bounds__(256) void dec_s3(const float* __restrict__ in,
                                              const float* __restrict__ wt,
                                              const float* __restrict__ bs,
                                              float* __restrict__ out) {
  int t = blockIdx.x * 256 + threadIdx.x;
  int ox = t & 127, oy = (t >> 7) & 127, n = t >> 14;
  float a = bs[0];
#pragma unroll
  for (int ky = 0; ky < 3; ++ky) {
    int iy = oy + ky - 1;
    if ((unsigned)iy >= 128u) continue;
#pragma unroll
    for (int kx = 0; kx < 3; ++kx) {
      int ix = ox + kx - 1;
      if ((unsigned)ix >= 128u) continue;
      const float4* xp = (const float4*)(in + ((n * 128 + iy) * 128 + ix) * 16);
      const float4* wp = (const float4*)(wt + (ky * 3 + kx) * 16);
#pragma unroll
      for (int i4 = 0; i4 < 4; ++i4) {
        float4 xv = xp[i4], wv = wp[i4];
        a = fmaf(xv.x, wv.x, a);
        a = fmaf(xv.y, wv.y, a);
        a = fmaf(xv.z, wv.z, a);
        a = fmaf(xv.w, wv.w, a);
      }
    }
  }
  out[n * 16384 + oy * 128 + ox] = a;
}

// ---------------- host ----------------
extern "C" void kernel_launch(void* const* d_in, const int* in_sizes, int n_in,
                              void* d_out, int out_size, void* d_ws, size_t ws_size,
                              hipStream_t stream) {
  (void)in_sizes; (void)n_in; (void)out_size; (void)ws_size;
  (void)hipFuncSetAttribute((const void*)ode_persist,
                            hipFuncAttributeMaxDynamicSharedMemorySize, CONV_LDS);

  uint8_t* ws = (uint8_t*)d_ws;
  uint32_t* S0 = (uint32_t*)(ws + 0);         // packed state, 1 MB each
  uint32_t* S1 = (uint32_t*)(ws + 1048576);
  uint32_t* T0 = (uint32_t*)(ws + 2097152);
  uint32_t* T1 = (uint32_t*)(ws + 3145728);
  unsigned short* WIMG = (unsigned short*)(ws + 4194304);   // 589824 B
  float* s1wt = (float*)(ws + 4784128);
  float* s2wt = (float*)(ws + 4915200);
  float* s3wt = (float*)(ws + 4947968);
  int* progress = (int*)(ws + 4980736);       // 64 x int
  float* outs = (float*)(ws + 5242880);       // 10 x 262144 f32
  float* d1 = (float*)(ws + 16777216);        // decoder scratch 2 MB
  float* d2 = (float*)(ws + 18874368);        // decoder scratch 4 MB

  const float* h_s0 = (const float*)d_in[0];
  const float* wode[4] = {(const float*)d_in[1], (const float*)d_in[3],
                          (const float*)d_in[5], (const float*)d_in[7]};
  const float* bode[4] = {(const float*)d_in[2], (const float*)d_in[4],
                          (const float*)d_in[6], (const float*)d_in[8]};
  const float* s1w = (const float*)d_in[9];
  const float* s1b = (const float*)d_in[10];
  const float* s2w = (const float*)d_in[11];
  const float* s2b = (const float*)d_in[12];
  const float* s3w = (const float*)d_in[13];
  const float* s3b = (const float*)d_in[14];

  (void)hipMemsetAsync(progress, 0, 64 * sizeof(int), stream);
  prep_weights<<<737, 256, 0, stream>>>(wode[0], wode[1], wode[2], wode[3],
                                        s1w, s2w, s3w, WIMG, s1wt, s2wt, s3wt);
  prep_state<<<1024, 256, 0, stream>>>(h_s0, S0, outs);

  ode_persist<<<dim3(64), dim3(1024), CONV_LDS, stream>>>(
      WIMG, bode[0], bode[1], bode[2], bode[3],
      S0, S1, T0, T1, outs, progress);

  for (int t0 = 0; t0 < 10; ++t0) {
    dec_s1<<<2048, 256, 0, stream>>>(outs + (size_t)t0 * 262144, s1wt, s1b, d1);
    dec_s2<<<4096, 256, 0, stream>>>(d1, s2wt, s2b, d2);
    dec_s3<<<256, 256, 0, stream>>>(d2, s3wt, s3b,
                                    (float*)d_out + (size_t)t0 * 65536);
  }
}